// Round 1
// baseline (2004.487 us; speedup 1.0000x reference)
//
#include <hip/hip_runtime.h>
#include <math.h>

#define Nn 10000
#define En 160000
#define NF 5
#define EF 3
#define Hh 8
#define Cc 128
#define HC 1024
#define Gg 16

#define BM 128
#define BN 128
#define BK 16

// ---------------- preprocessing ----------------

__global__ void deg_sum_k(const int* __restrict__ dst, const float* __restrict__ ea,
                          int* __restrict__ cnt, float* __restrict__ sum_ea) {
    int e = blockIdx.x * 256 + threadIdx.x;
    if (e >= En) return;
    int d = dst[e];
    atomicAdd(&cnt[d], 1);
    atomicAdd(&sum_ea[d * 3 + 0], ea[e * 3 + 0]);
    atomicAdd(&sum_ea[d * 3 + 1], ea[e * 3 + 1]);
    atomicAdd(&sum_ea[d * 3 + 2], ea[e * 3 + 2]);
}

__global__ void finish_loop_k(const int* __restrict__ cnt, float* __restrict__ loop_attr) {
    int n = blockIdx.x * 256 + threadIdx.x;
    if (n >= Nn) return;
    float s = 1.0f / fmaxf((float)cnt[n], 1.0f);
    loop_attr[n * 3 + 0] *= s;
    loop_attr[n * 3 + 1] *= s;
    loop_attr[n * 3 + 2] *= s;
}

__global__ __launch_bounds__(1024) void scan_k(const int* __restrict__ cnt,
                                               int* __restrict__ rowptr,
                                               int* __restrict__ fillptr) {
    __shared__ int sh[1024];
    int tid = threadIdx.x;
    int base = 0;
    for (int chunk = 0; chunk < Nn; chunk += 1024) {
        int i = chunk + tid;
        int v = (i < Nn) ? cnt[i] : 0;
        sh[tid] = v;
        __syncthreads();
        for (int off = 1; off < 1024; off <<= 1) {
            int t = (tid >= off) ? sh[tid - off] : 0;
            __syncthreads();
            sh[tid] += t;
            __syncthreads();
        }
        int excl = sh[tid] - v;
        if (i < Nn) { rowptr[i] = base + excl; fillptr[i] = base + excl; }
        int total = sh[1023];
        __syncthreads();
        base += total;
    }
    if (tid == 0) rowptr[Nn] = base;
}

__global__ void csr_fill_k(const int* __restrict__ dst, int* __restrict__ fillptr,
                           int* __restrict__ csr) {
    int e = blockIdx.x * 256 + threadIdx.x;
    if (e >= En) return;
    int d = dst[e];
    int pos = atomicAdd(&fillptr[d], 1);
    csr[pos] = e;
}

// ---------------- GEMMs ----------------

// layer-1: K=5 tiny GEMM, one block per node row
__global__ void gemm_k5(const float* __restrict__ x, const float* __restrict__ Wm,
                        float* __restrict__ out) {
    int n = blockIdx.x;
    int tid = threadIdx.x;
    __shared__ float xr[8];
    if (tid < NF) xr[tid] = x[n * NF + tid];
    __syncthreads();
    float x0 = xr[0], x1 = xr[1], x2 = xr[2], x3 = xr[3], x4 = xr[4];
    for (int j = tid; j < HC; j += 256) {
        float v = x0 * Wm[j] + x1 * Wm[HC + j] + x2 * Wm[2 * HC + j]
                + x3 * Wm[3 * HC + j] + x4 * Wm[4 * HC + j];
        out[(size_t)n * HC + j] = v;
    }
}

// fp32 tiled GEMM: C[M,Ncols] = A[M,K] * B[K,Ncols]; Ncols,K multiples of tile
__global__ __launch_bounds__(256) void gemm_f32(const float* __restrict__ A,
                                                const float* __restrict__ B,
                                                float* __restrict__ Cmat,
                                                int M, int K, int Ncols) {
    __shared__ float As[BK][BM + 4];
    __shared__ float Bs[BK][BN + 4];
    int bx = blockIdx.x, by = blockIdx.y;
    int tid = threadIdx.x;
    int tx = tid & 15, ty = tid >> 4;
    int row0 = by * BM, col0 = bx * BN;
    float acc[8][8];
#pragma unroll
    for (int i = 0; i < 8; ++i)
#pragma unroll
        for (int j = 0; j < 8; ++j) acc[i][j] = 0.f;

    for (int k0 = 0; k0 < K; k0 += BK) {
#pragma unroll
        for (int i = 0; i < 2; ++i) {
            int idx = tid + i * 256;       // 0..511 -> 512 float4 of A tile
            int r = idx >> 2, kq = idx & 3;
            int grow = row0 + r;
            float4 v = make_float4(0.f, 0.f, 0.f, 0.f);
            if (grow < M) v = *(const float4*)&A[(size_t)grow * K + k0 + kq * 4];
            As[kq * 4 + 0][r] = v.x;
            As[kq * 4 + 1][r] = v.y;
            As[kq * 4 + 2][r] = v.z;
            As[kq * 4 + 3][r] = v.w;
        }
#pragma unroll
        for (int i = 0; i < 2; ++i) {
            int idx = tid + i * 256;       // 512 float4 of B tile
            int r = idx >> 5, cq = idx & 31;
            float4 v = *(const float4*)&B[(size_t)(k0 + r) * Ncols + col0 + cq * 4];
            *(float4*)&Bs[r][cq * 4] = v;
        }
        __syncthreads();
#pragma unroll
        for (int k = 0; k < BK; ++k) {
            float a[8], b[8];
            *(float4*)&a[0] = *(const float4*)&As[k][ty * 8];
            *(float4*)&a[4] = *(const float4*)&As[k][ty * 8 + 4];
            *(float4*)&b[0] = *(const float4*)&Bs[k][tx * 8];
            *(float4*)&b[4] = *(const float4*)&Bs[k][tx * 8 + 4];
#pragma unroll
            for (int i = 0; i < 8; ++i)
#pragma unroll
                for (int j = 0; j < 8; ++j) acc[i][j] = fmaf(a[i], b[j], acc[i][j]);
        }
        __syncthreads();
    }
#pragma unroll
    for (int i = 0; i < 8; ++i) {
        int grow = row0 + ty * 8 + i;
        if (grow < M) {
            float4 v0 = make_float4(acc[i][0], acc[i][1], acc[i][2], acc[i][3]);
            float4 v1 = make_float4(acc[i][4], acc[i][5], acc[i][6], acc[i][7]);
            *(float4*)&Cmat[(size_t)grow * Ncols + col0 + tx * 8] = v0;
            *(float4*)&Cmat[(size_t)grow * Ncols + col0 + tx * 8 + 4] = v1;
        }
    }
}

// ---------------- attention ----------------

// w_ae[f][h] = sum_c We[f, h*C+c] * a_e[h, c]   (3x8)
__global__ void wae_k(const float* __restrict__ We, const float* __restrict__ a_e,
                      float* __restrict__ w_ae) {
    int t = threadIdx.x;
    if (t >= EF * Hh) return;
    int f = t >> 3, h = t & 7;
    float s = 0.f;
    for (int c = 0; c < Cc; ++c) s += We[f * HC + h * Cc + c] * a_e[h * Cc + c];
    w_ae[f * Hh + h] = s;
}

// a_src[n,h], a_dst[n,h]: one wave per (n,h)
__global__ __launch_bounds__(256) void attn_nodes_k(const float* __restrict__ xl,
                                                    const float* __restrict__ a_s,
                                                    const float* __restrict__ a_d,
                                                    float* __restrict__ a_src,
                                                    float* __restrict__ a_dst) {
    int wid = (blockIdx.x * 256 + threadIdx.x) >> 6;
    int lane = threadIdx.x & 63;
    if (wid >= Nn * Hh) return;
    int n = wid >> 3, h = wid & 7;
    const float* row = xl + (size_t)n * HC + h * Cc;
    float r0 = row[lane], r1 = row[lane + 64];
    float s1 = r0 * a_s[h * Cc + lane] + r1 * a_s[h * Cc + lane + 64];
    float s2 = r0 * a_d[h * Cc + lane] + r1 * a_d[h * Cc + lane + 64];
#pragma unroll
    for (int off = 32; off; off >>= 1) {
        s1 += __shfl_xor(s1, off);
        s2 += __shfl_xor(s2, off);
    }
    if (lane == 0) { a_src[wid] = s1; a_dst[wid] = s2; }
}

__global__ void alpha_edge_k(const int* __restrict__ src, const int* __restrict__ dst,
                             const float* __restrict__ ea,
                             const float* __restrict__ a_src, const float* __restrict__ a_dst,
                             const float* __restrict__ w_ae, float* __restrict__ alphaE) {
    int e = blockIdx.x * 256 + threadIdx.x;
    if (e >= En) return;
    int s = src[e], d = dst[e];
    float f0 = ea[e * 3 + 0], f1 = ea[e * 3 + 1], f2 = ea[e * 3 + 2];
#pragma unroll
    for (int h = 0; h < Hh; ++h) {
        float v = a_src[s * Hh + h] + a_dst[d * Hh + h]
                + f0 * w_ae[h] + f1 * w_ae[Hh + h] + f2 * w_ae[2 * Hh + h];
        alphaE[(size_t)e * Hh + h] = (v > 0.f) ? v : 0.2f * v;
    }
}

__global__ void alpha_self_k(const float* __restrict__ loop_attr,
                             const float* __restrict__ a_src, const float* __restrict__ a_dst,
                             const float* __restrict__ w_ae, float* __restrict__ alphaSelf) {
    int n = blockIdx.x * 256 + threadIdx.x;
    if (n >= Nn) return;
    float f0 = loop_attr[n * 3 + 0], f1 = loop_attr[n * 3 + 1], f2 = loop_attr[n * 3 + 2];
#pragma unroll
    for (int h = 0; h < Hh; ++h) {
        float v = a_src[n * Hh + h] + a_dst[n * Hh + h]
                + f0 * w_ae[h] + f1 * w_ae[Hh + h] + f2 * w_ae[2 * Hh + h];
        alphaSelf[n * Hh + h] = (v > 0.f) ? v : 0.2f * v;
    }
}

__device__ __forceinline__ float elu_f(float v) {
    return (v > 0.f) ? v : expm1f(v);
}

// one wave per (n,h): segment softmax + weighted gather of xl[src]
__global__ __launch_bounds__(256) void aggregate_k(const float* __restrict__ xl,
                                                   const float* __restrict__ alphaE,
                                                   const float* __restrict__ alphaSelf,
                                                   const int* __restrict__ rowptr,
                                                   const int* __restrict__ csr,
                                                   const int* __restrict__ src,
                                                   const float* __restrict__ bias,
                                                   float* __restrict__ out,
                                                   int raw_mode) {
    int wid = (blockIdx.x * 256 + threadIdx.x) >> 6;
    int lane = threadIdx.x & 63;
    if (wid >= Nn * Hh) return;
    int n = wid >> 3, h = wid & 7;
    int beg = rowptr[n], end = rowptr[n + 1];

    float aself = alphaSelf[wid];
    float m = aself;
    for (int i = beg + lane; i < end; i += 64) m = fmaxf(m, alphaE[(size_t)csr[i] * Hh + h]);
#pragma unroll
    for (int off = 32; off; off >>= 1) m = fmaxf(m, __shfl_xor(m, off));

    float s = (lane == 0) ? __expf(aself - m) : 0.f;
    for (int i = beg + lane; i < end; i += 64) s += __expf(alphaE[(size_t)csr[i] * Hh + h] - m);
#pragma unroll
    for (int off = 32; off; off >>= 1) s += __shfl_xor(s, off);
    float inv = 1.f / (s + 1e-16f);

    const float* xrow = xl + (size_t)n * HC + h * Cc;
    float wslf = __expf(aself - m) * inv;
    float acc0 = wslf * xrow[lane];
    float acc1 = wslf * xrow[lane + 64];
    for (int i = beg; i < end; ++i) {
        int e = csr[i];
        int sn = src[e];
        float w = __expf(alphaE[(size_t)e * Hh + h] - m) * inv;
        const float* r = xl + (size_t)sn * HC + h * Cc;
        acc0 = fmaf(w, r[lane], acc0);
        acc1 = fmaf(w, r[lane + 64], acc1);
    }
    size_t o0 = (size_t)n * HC + h * Cc + lane;
    if (raw_mode) {
        out[o0] = acc0;
        out[o0 + 64] = acc1;
    } else {
        out[o0] = elu_f(acc0 + bias[h * Cc + lane]);
        out[o0 + 64] = elu_f(acc1 + bias[h * Cc + lane + 64]);
    }
}

// layer4 epilogue: mean over heads + bias + elu
__global__ void mean_heads_k(const float* __restrict__ raw, const float* __restrict__ bias,
                             float* __restrict__ hfinal) {
    int idx = blockIdx.x * 256 + threadIdx.x;
    if (idx >= Nn * Cc) return;
    int n = idx >> 7, c = idx & 127;
    float s = 0.f;
#pragma unroll
    for (int h = 0; h < Hh; ++h) s += raw[(size_t)n * HC + h * Cc + c];
    hfinal[idx] = elu_f(s * 0.125f + bias[c]);
}

__global__ void pool_k(const float* __restrict__ hfinal, const int* __restrict__ batch,
                       float* __restrict__ pooled, float* __restrict__ cntg) {
    int idx = blockIdx.x * 256 + threadIdx.x;
    if (idx >= Nn * Cc) return;
    int n = idx >> 7, c = idx & 127;
    int g = batch[n];
    atomicAdd(&pooled[g * Cc + c], hfinal[idx]);
    if (c == 0) atomicAdd(&cntg[g], 1.0f);
}

__global__ void final_k(const float* __restrict__ pooled, const float* __restrict__ cntg,
                        const float* __restrict__ lin_w, const float* __restrict__ lin_b,
                        float* __restrict__ out) {
    int lane = threadIdx.x & 63;
    int w = threadIdx.x >> 6;
    for (int g = w; g < Gg; g += 4) {
        float v = pooled[g * Cc + lane] * lin_w[lane]
                + pooled[g * Cc + lane + 64] * lin_w[lane + 64];
#pragma unroll
        for (int off = 32; off; off >>= 1) v += __shfl_xor(v, off);
        if (lane == 0) out[g] = v / fmaxf(cntg[g], 1.0f) + lin_b[0];
    }
}

// ---------------- launch ----------------

extern "C" void kernel_launch(void* const* d_in, const int* in_sizes, int n_in,
                              void* d_out, int out_size, void* d_ws, size_t ws_size,
                              hipStream_t stream) {
    const float* x = (const float*)d_in[0];
    const int* ei = (const int*)d_in[1];
    const float* ea = (const float*)d_in[2];
    const int* batch = (const int*)d_in[3];
    const float *Wl[4], *Wel[4], *asl[4], *adl[4], *ael[4], *bl[4];
    for (int l = 0; l < 4; ++l) {
        Wl[l] = (const float*)d_in[4 + 6 * l];
        Wel[l] = (const float*)d_in[5 + 6 * l];
        asl[l] = (const float*)d_in[6 + 6 * l];
        adl[l] = (const float*)d_in[7 + 6 * l];
        ael[l] = (const float*)d_in[8 + 6 * l];
        bl[l] = (const float*)d_in[9 + 6 * l];
    }
    const float* lin_w = (const float*)d_in[28];
    const float* lin_b = (const float*)d_in[29];
    const int* srcA = ei;
    const int* dstA = ei + En;

    float* Wp = (float*)d_ws;
    size_t o = 0;
    float* bigA = Wp + o; o += (size_t)Nn * HC;   // xl buffer
    float* bigB = Wp + o; o += (size_t)Nn * HC;   // h ping-pong (aggregate output)
    float* loop_attr = Wp + o; o += Nn * 3;
    int* cnt = (int*)(Wp + o); o += Nn;
    int* rowptr = (int*)(Wp + o); o += Nn + 1;
    int* fillptr = (int*)(Wp + o); o += Nn;
    int* csr = (int*)(Wp + o); o += En;
    float* a_srcB = Wp + o; o += Nn * Hh;
    float* a_dstB = Wp + o; o += Nn * Hh;
    float* alphaE = Wp + o; o += (size_t)En * Hh;
    float* alphaSelf = Wp + o; o += Nn * Hh;
    float* w_ae = Wp + o; o += 32;
    float* hfinal = Wp + o; o += Nn * Cc;
    float* pooled = Wp + o; o += Gg * Cc;
    float* cntg = Wp + o; o += Gg;

    hipMemsetAsync(cnt, 0, Nn * sizeof(int), stream);
    hipMemsetAsync(loop_attr, 0, Nn * 3 * sizeof(float), stream);
    hipMemsetAsync(pooled, 0, (Gg * Cc + Gg) * sizeof(float), stream);

    deg_sum_k<<<(En + 255) / 256, 256, 0, stream>>>(dstA, ea, cnt, loop_attr);
    finish_loop_k<<<(Nn + 255) / 256, 256, 0, stream>>>(cnt, loop_attr);
    scan_k<<<1, 1024, 0, stream>>>(cnt, rowptr, fillptr);
    csr_fill_k<<<(En + 255) / 256, 256, 0, stream>>>(dstA, fillptr, csr);

    for (int l = 0; l < 4; ++l) {
        if (l == 0)
            gemm_k5<<<Nn, 256, 0, stream>>>(x, Wl[0], bigA);
        else
            gemm_f32<<<dim3(HC / BN, (Nn + BM - 1) / BM), 256, 0, stream>>>(
                bigB, Wl[l], bigA, Nn, HC, HC);
        wae_k<<<1, 64, 0, stream>>>(Wel[l], ael[l], w_ae);
        attn_nodes_k<<<(Nn * Hh) / 4, 256, 0, stream>>>(bigA, asl[l], adl[l], a_srcB, a_dstB);
        alpha_edge_k<<<(En + 255) / 256, 256, 0, stream>>>(srcA, dstA, ea, a_srcB, a_dstB,
                                                           w_ae, alphaE);
        alpha_self_k<<<(Nn + 255) / 256, 256, 0, stream>>>(loop_attr, a_srcB, a_dstB,
                                                           w_ae, alphaSelf);
        aggregate_k<<<(Nn * Hh) / 4, 256, 0, stream>>>(bigA, alphaE, alphaSelf, rowptr, csr,
                                                       srcA, bl[l], bigB, (l == 3) ? 1 : 0);
    }
    mean_heads_k<<<(Nn * Cc) / 256, 256, 0, stream>>>(bigB, bl[3], hfinal);
    pool_k<<<(Nn * Cc) / 256, 256, 0, stream>>>(hfinal, batch, pooled, cntg);
    final_k<<<1, 256, 0, stream>>>(pooled, cntg, lin_w, lin_b, (float*)d_out);
}

// Round 2
// 1339.129 us; speedup vs baseline: 1.4969x; 1.4969x over previous
//
#include <hip/hip_runtime.h>
#include <math.h>

#define Nn 10000
#define En 160000
#define NF 5
#define EF 3
#define Hh 8
#define Cc 128
#define HC 1024
#define Gg 16

#define Mpad 10112   // 79 * 128

typedef __attribute__((ext_vector_type(8))) short short8;
typedef __attribute__((ext_vector_type(4))) float f32x4;

// ---------------- helpers ----------------

__device__ __forceinline__ unsigned short bf16_rn(float x) {
    unsigned int b = __float_as_uint(x);
    unsigned int r = b + 0x7FFFu + ((b >> 16) & 1u);
    return (unsigned short)(r >> 16);
}
__device__ __forceinline__ float bf16_to_f(unsigned short h) {
    return __uint_as_float(((unsigned int)h) << 16);
}

__device__ __forceinline__ void gl_lds16(const void* g, void* l) {
    __builtin_amdgcn_global_load_lds((const __attribute__((address_space(1))) void*)g,
                                     (__attribute__((address_space(3))) void*)l, 16, 0, 0);
}

__device__ __forceinline__ float elu_f(float v) {
    return (v > 0.f) ? v : expm1f(v);
}

// ---------------- preprocessing ----------------

__global__ void deg_sum_k(const int* __restrict__ dst, const float* __restrict__ ea,
                          int* __restrict__ cnt, float* __restrict__ sum_ea) {
    int e = blockIdx.x * 256 + threadIdx.x;
    if (e >= En) return;
    int d = dst[e];
    atomicAdd(&cnt[d], 1);
    atomicAdd(&sum_ea[d * 3 + 0], ea[e * 3 + 0]);
    atomicAdd(&sum_ea[d * 3 + 1], ea[e * 3 + 1]);
    atomicAdd(&sum_ea[d * 3 + 2], ea[e * 3 + 2]);
}

__global__ void finish_loop_k(const int* __restrict__ cnt, float* __restrict__ loop_attr) {
    int n = blockIdx.x * 256 + threadIdx.x;
    if (n >= Nn) return;
    float s = 1.0f / fmaxf((float)cnt[n], 1.0f);
    loop_attr[n * 3 + 0] *= s;
    loop_attr[n * 3 + 1] *= s;
    loop_attr[n * 3 + 2] *= s;
}

__global__ __launch_bounds__(1024) void scan_k(const int* __restrict__ cnt,
                                               int* __restrict__ rowptr,
                                               int* __restrict__ fillptr) {
    __shared__ int sh[1024];
    int tid = threadIdx.x;
    int base = 0;
    for (int chunk = 0; chunk < Nn; chunk += 1024) {
        int i = chunk + tid;
        int v = (i < Nn) ? cnt[i] : 0;
        sh[tid] = v;
        __syncthreads();
        for (int off = 1; off < 1024; off <<= 1) {
            int t = (tid >= off) ? sh[tid - off] : 0;
            __syncthreads();
            sh[tid] += t;
            __syncthreads();
        }
        int excl = sh[tid] - v;
        if (i < Nn) { rowptr[i] = base + excl; fillptr[i] = base + excl; }
        int total = sh[1023];
        __syncthreads();
        base += total;
    }
    if (tid == 0) rowptr[Nn] = base;
}

// CSR fill: also records position of each edge and src node per position
__global__ void csr_fill_k(const int* __restrict__ src, const int* __restrict__ dst,
                           int* __restrict__ fillptr, int* __restrict__ epos,
                           int* __restrict__ srcP) {
    int e = blockIdx.x * 256 + threadIdx.x;
    if (e >= En) return;
    int d = dst[e];
    int pos = atomicAdd(&fillptr[d], 1);
    epos[e] = pos;
    srcP[pos] = src[e];
}

// ---------------- precision-split conversions ----------------

// activations [M][1024] fp32 -> A2 [Mpad][2048] bf16 (hi | lo)
__global__ void asplit_k(const float* __restrict__ A, unsigned short* __restrict__ A2) {
    int idx = blockIdx.x * 256 + threadIdx.x;
    if (idx >= Nn * HC) return;
    int m = idx >> 10, k = idx & 1023;
    float x = A[idx];
    unsigned short hb = bf16_rn(x);
    float lo = x - bf16_to_f(hb);
    A2[(size_t)m * 2048 + k] = hb;
    A2[(size_t)m * 2048 + 1024 + k] = bf16_rn(lo);
}

// W [1024][1024] fp32 -> Wt2 [1024 (n)][2048 (k: hi|lo)] bf16, transposed
__global__ __launch_bounds__(1024) void wsplit_k(const float* __restrict__ W,
                                                 unsigned short* __restrict__ Wt2) {
    __shared__ float tile[32][33];
    int nb = blockIdx.x * 32, kb = blockIdx.y * 32;
    tile[threadIdx.y][threadIdx.x] = W[(size_t)(kb + threadIdx.y) * HC + nb + threadIdx.x];
    __syncthreads();
    float x = tile[threadIdx.x][threadIdx.y];   // W[kb+tx][nb+ty]
    unsigned short hb = bf16_rn(x);
    float lo = x - bf16_to_f(hb);
    int n = nb + threadIdx.y, k = kb + threadIdx.x;
    Wt2[(size_t)n * 2048 + k] = hb;
    Wt2[(size_t)n * 2048 + 1024 + k] = bf16_rn(lo);
}

// ---------------- GEMMs ----------------

// layer-1: K=5 tiny GEMM
__global__ void gemm_k5(const float* __restrict__ x, const float* __restrict__ Wm,
                        float* __restrict__ out) {
    int n = blockIdx.x;
    int tid = threadIdx.x;
    __shared__ float xr[8];
    if (tid < NF) xr[tid] = x[n * NF + tid];
    __syncthreads();
    float x0 = xr[0], x1 = xr[1], x2 = xr[2], x3 = xr[3], x4 = xr[4];
    for (int j = tid; j < HC; j += 256) {
        float v = x0 * Wm[j] + x1 * Wm[HC + j] + x2 * Wm[2 * HC + j]
                + x3 * Wm[3 * HC + j] + x4 * Wm[4 * HC + j];
        out[(size_t)n * HC + j] = v;
    }
}

// bf16 MFMA GEMM with 3-term precision split:
// C[M][1024] = sum over K'=3072 of A'[m][k'] * B'[k'][n]
//   term 0: A_hi * W_hi ; term 1: A_hi * W_lo ; term 2: A_lo * W_hi
// A2: [Mpad][2048] (hi|lo along k), Bt2: [1024][2048] (hi|lo along k, n-major)
__global__ __launch_bounds__(256) void gemm_mfma(const unsigned short* __restrict__ A2,
                                                 const unsigned short* __restrict__ Bt2,
                                                 float* __restrict__ C) {
    __shared__ short As[128 * 32];   // [row][k], 64B rows
    __shared__ short Bs[128 * 32];
    int tid = threadIdx.x;
    int wave = tid >> 6, lane = tid & 63;
    int wr = wave >> 1, wc = wave & 1;
    int row0 = blockIdx.y * 128;
    int col0 = blockIdx.x * 128;

    f32x4 acc[4][4];
#pragma unroll
    for (int i = 0; i < 4; ++i)
#pragma unroll
        for (int j = 0; j < 4; ++j) acc[i][j] = (f32x4){0.f, 0.f, 0.f, 0.f};

    int srow = lane >> 2;          // 0..15
    int scol = (lane & 3) * 8;     // bf16 index within 32-wide k-tile
    int fr = lane & 15;
    int fk = (lane >> 4) * 8;

    for (int k0 = 0; k0 < 3072; k0 += 32) {
        int term = k0 >> 10;
        int kin = k0 & 1023;
        int ak = (term == 2 ? 1024 : 0) + kin;
        int bk = (term == 1 ? 1024 : 0) + kin;

        // stage 16KB: 8 A-chunks + 8 B-chunks of 1KB; wave w does A{w,w+4}, B{w,w+4}
#pragma unroll
        for (int cc = 0; cc < 2; ++cc) {
            int c = wave + cc * 4;
            int r = c * 16 + srow;
            gl_lds16(A2 + (size_t)(row0 + r) * 2048 + ak + scol, &As[c * 512 + lane * 8]);
            gl_lds16(Bt2 + (size_t)(col0 + r) * 2048 + bk + scol, &Bs[c * 512 + lane * 8]);
        }
        __syncthreads();

        short8 af[4], bfr[4];
#pragma unroll
        for (int i = 0; i < 4; ++i)
            af[i] = *(const short8*)&As[(wr * 64 + i * 16 + fr) * 32 + fk];
#pragma unroll
        for (int j = 0; j < 4; ++j)
            bfr[j] = *(const short8*)&Bs[(wc * 64 + j * 16 + fr) * 32 + fk];
#pragma unroll
        for (int i = 0; i < 4; ++i)
#pragma unroll
            for (int j = 0; j < 4; ++j)
                acc[i][j] = __builtin_amdgcn_mfma_f32_16x16x32_bf16(af[i], bfr[j], acc[i][j],
                                                                    0, 0, 0);
        __syncthreads();
    }

    // C/D layout (verified m89): col = lane&15, row = (lane>>4)*4 + reg
    int cn = lane & 15, rq = (lane >> 4) * 4;
#pragma unroll
    for (int i = 0; i < 4; ++i) {
        int rbase = row0 + wr * 64 + i * 16 + rq;
#pragma unroll
        for (int j = 0; j < 4; ++j) {
            int col = col0 + wc * 64 + j * 16 + cn;
#pragma unroll
            for (int r = 0; r < 4; ++r) {
                int row = rbase + r;
                if (row < Nn) C[(size_t)row * HC + col] = acc[i][j][r];
            }
        }
    }
}

// ---------------- attention ----------------

// w_ae[f][h] = sum_c We[f, h*C+c] * a_e[h, c]   (3x8)
__global__ void wae_k(const float* __restrict__ We, const float* __restrict__ a_e,
                      float* __restrict__ w_ae) {
    int t = threadIdx.x;
    if (t >= EF * Hh) return;
    int f = t >> 3, h = t & 7;
    float s = 0.f;
    for (int c = 0; c < Cc; ++c) s += We[f * HC + h * Cc + c] * a_e[h * Cc + c];
    w_ae[f * Hh + h] = s;
}

__global__ __launch_bounds__(256) void attn_nodes_k(const float* __restrict__ xl,
                                                    const float* __restrict__ a_s,
                                                    const float* __restrict__ a_d,
                                                    float* __restrict__ a_src,
                                                    float* __restrict__ a_dst) {
    int wid = (blockIdx.x * 256 + threadIdx.x) >> 6;
    int lane = threadIdx.x & 63;
    if (wid >= Nn * Hh) return;
    int n = wid >> 3, h = wid & 7;
    const float* row = xl + (size_t)n * HC + h * Cc;
    float r0 = row[lane], r1 = row[lane + 64];
    float s1 = r0 * a_s[h * Cc + lane] + r1 * a_s[h * Cc + lane + 64];
    float s2 = r0 * a_d[h * Cc + lane] + r1 * a_d[h * Cc + lane + 64];
#pragma unroll
    for (int off = 32; off; off >>= 1) {
        s1 += __shfl_xor(s1, off);
        s2 += __shfl_xor(s2, off);
    }
    if (lane == 0) { a_src[wid] = s1; a_dst[wid] = s2; }
}

// writes alpha into CSR-position order: alphaP[pos][h]
__global__ void alpha_edge_k(const int* __restrict__ src, const int* __restrict__ dst,
                             const int* __restrict__ epos, const float* __restrict__ ea,
                             const float* __restrict__ a_src, const float* __restrict__ a_dst,
                             const float* __restrict__ w_ae, float* __restrict__ alphaP) {
    int e = blockIdx.x * 256 + threadIdx.x;
    if (e >= En) return;
    int s = src[e], d = dst[e];
    int pos = epos[e];
    float f0 = ea[e * 3 + 0], f1 = ea[e * 3 + 1], f2 = ea[e * 3 + 2];
#pragma unroll
    for (int h = 0; h < Hh; ++h) {
        float v = a_src[s * Hh + h] + a_dst[d * Hh + h]
                + f0 * w_ae[h] + f1 * w_ae[Hh + h] + f2 * w_ae[2 * Hh + h];
        alphaP[(size_t)pos * Hh + h] = (v > 0.f) ? v : 0.2f * v;
    }
}

__global__ void alpha_self_k(const float* __restrict__ loop_attr,
                             const float* __restrict__ a_src, const float* __restrict__ a_dst,
                             const float* __restrict__ w_ae, float* __restrict__ alphaSelf) {
    int n = blockIdx.x * 256 + threadIdx.x;
    if (n >= Nn) return;
    float f0 = loop_attr[n * 3 + 0], f1 = loop_attr[n * 3 + 1], f2 = loop_attr[n * 3 + 2];
#pragma unroll
    for (int h = 0; h < Hh; ++h) {
        float v = a_src[n * Hh + h] + a_dst[n * Hh + h]
                + f0 * w_ae[h] + f1 * w_ae[Hh + h] + f2 * w_ae[2 * Hh + h];
        alphaSelf[n * Hh + h] = (v > 0.f) ? v : 0.2f * v;
    }
}

// one wave per (n,h): segment softmax + weighted gather of xl[src]
__global__ __launch_bounds__(256) void aggregate_k(const float* __restrict__ xl,
                                                   const float* __restrict__ alphaP,
                                                   const float* __restrict__ alphaSelf,
                                                   const int* __restrict__ rowptr,
                                                   const int* __restrict__ srcP,
                                                   const float* __restrict__ bias,
                                                   float* __restrict__ out,
                                                   int raw_mode) {
    int wid = (blockIdx.x * 256 + threadIdx.x) >> 6;
    int lane = threadIdx.x & 63;
    if (wid >= Nn * Hh) return;
    int n = wid >> 3, h = wid & 7;
    int beg = rowptr[n], end = rowptr[n + 1];

    float aself = alphaSelf[wid];
    float m = aself;
    for (int i = beg + lane; i < end; i += 64) m = fmaxf(m, alphaP[(size_t)i * Hh + h]);
#pragma unroll
    for (int off = 32; off; off >>= 1) m = fmaxf(m, __shfl_xor(m, off));

    float s = (lane == 0) ? __expf(aself - m) : 0.f;
    for (int i = beg + lane; i < end; i += 64) s += __expf(alphaP[(size_t)i * Hh + h] - m);
#pragma unroll
    for (int off = 32; off; off >>= 1) s += __shfl_xor(s, off);
    float inv = 1.f / (s + 1e-16f);

    const float* xrow = xl + (size_t)n * HC + h * Cc;
    float wslf = __expf(aself - m) * inv;
    float acc0 = wslf * xrow[lane];
    float acc1 = wslf * xrow[lane + 64];
    for (int i = beg; i < end; ++i) {
        int sn = srcP[i];
        float w = __expf(alphaP[(size_t)i * Hh + h] - m) * inv;
        const float* r = xl + (size_t)sn * HC + h * Cc;
        acc0 = fmaf(w, r[lane], acc0);
        acc1 = fmaf(w, r[lane + 64], acc1);
    }
    size_t o0 = (size_t)n * HC + h * Cc + lane;
    if (raw_mode) {
        out[o0] = acc0;
        out[o0 + 64] = acc1;
    } else {
        out[o0] = elu_f(acc0 + bias[h * Cc + lane]);
        out[o0 + 64] = elu_f(acc1 + bias[h * Cc + lane + 64]);
    }
}

// layer4 epilogue: mean over heads + bias + elu
__global__ void mean_heads_k(const float* __restrict__ raw, const float* __restrict__ bias,
                             float* __restrict__ hfinal) {
    int idx = blockIdx.x * 256 + threadIdx.x;
    if (idx >= Nn * Cc) return;
    int n = idx >> 7, c = idx & 127;
    float s = 0.f;
#pragma unroll
    for (int h = 0; h < Hh; ++h) s += raw[(size_t)n * HC + h * Cc + c];
    hfinal[idx] = elu_f(s * 0.125f + bias[c]);
}

__global__ void pool_k(const float* __restrict__ hfinal, const int* __restrict__ batch,
                       float* __restrict__ pooled, float* __restrict__ cntg) {
    int idx = blockIdx.x * 256 + threadIdx.x;
    if (idx >= Nn * Cc) return;
    int n = idx >> 7, c = idx & 127;
    int g = batch[n];
    atomicAdd(&pooled[g * Cc + c], hfinal[idx]);
    if (c == 0) atomicAdd(&cntg[g], 1.0f);
}

__global__ void final_k(const float* __restrict__ pooled, const float* __restrict__ cntg,
                        const float* __restrict__ lin_w, const float* __restrict__ lin_b,
                        float* __restrict__ out) {
    int lane = threadIdx.x & 63;
    int w = threadIdx.x >> 6;
    for (int g = w; g < Gg; g += 4) {
        float v = pooled[g * Cc + lane] * lin_w[lane]
                + pooled[g * Cc + lane + 64] * lin_w[lane + 64];
#pragma unroll
        for (int off = 32; off; off >>= 1) v += __shfl_xor(v, off);
        if (lane == 0) out[g] = v / fmaxf(cntg[g], 1.0f) + lin_b[0];
    }
}

// ---------------- launch ----------------

extern "C" void kernel_launch(void* const* d_in, const int* in_sizes, int n_in,
                              void* d_out, int out_size, void* d_ws, size_t ws_size,
                              hipStream_t stream) {
    const float* x = (const float*)d_in[0];
    const int* ei = (const int*)d_in[1];
    const float* ea = (const float*)d_in[2];
    const int* batch = (const int*)d_in[3];
    const float *Wl[4], *Wel[4], *asl[4], *adl[4], *ael[4], *bl[4];
    for (int l = 0; l < 4; ++l) {
        Wl[l] = (const float*)d_in[4 + 6 * l];
        Wel[l] = (const float*)d_in[5 + 6 * l];
        asl[l] = (const float*)d_in[6 + 6 * l];
        adl[l] = (const float*)d_in[7 + 6 * l];
        ael[l] = (const float*)d_in[8 + 6 * l];
        bl[l] = (const float*)d_in[9 + 6 * l];
    }
    const float* lin_w = (const float*)d_in[28];
    const float* lin_b = (const float*)d_in[29];
    const int* srcA = ei;
    const int* dstA = ei + En;

    float* Wp = (float*)d_ws;
    size_t o = 0;
    float* bigA = Wp + o; o += (size_t)Nn * HC;                 // xl (GEMM out)
    float* bigB = Wp + o; o += (size_t)Nn * HC;                 // h ping-pong
    unsigned short* A2 = (unsigned short*)(Wp + o); o += (size_t)Mpad * 2048 / 2;  // split acts
    unsigned short* Wt2 = (unsigned short*)(Wp + o); o += (size_t)HC * 2048 / 2;   // split weights
    float* loop_attr = Wp + o; o += Nn * 3;
    int* cnt = (int*)(Wp + o); o += Nn;
    int* rowptr = (int*)(Wp + o); o += Nn + 1;
    int* fillptr = (int*)(Wp + o); o += Nn;
    int* epos = (int*)(Wp + o); o += En;
    int* srcP = (int*)(Wp + o); o += En;
    float* a_srcB = Wp + o; o += Nn * Hh;
    float* a_dstB = Wp + o; o += Nn * Hh;
    float* alphaP = Wp + o; o += (size_t)En * Hh;
    float* alphaSelf = Wp + o; o += Nn * Hh;
    float* w_ae = Wp + o; o += 32;
    float* hfinal = Wp + o; o += Nn * Cc;
    float* pooled = Wp + o; o += Gg * Cc;
    float* cntg = Wp + o; o += Gg;

    hipMemsetAsync(cnt, 0, Nn * sizeof(int), stream);
    hipMemsetAsync(loop_attr, 0, Nn * 3 * sizeof(float), stream);
    hipMemsetAsync(pooled, 0, (Gg * Cc + Gg) * sizeof(float), stream);

    deg_sum_k<<<(En + 255) / 256, 256, 0, stream>>>(dstA, ea, cnt, loop_attr);
    finish_loop_k<<<(Nn + 255) / 256, 256, 0, stream>>>(cnt, loop_attr);
    scan_k<<<1, 1024, 0, stream>>>(cnt, rowptr, fillptr);
    csr_fill_k<<<(En + 255) / 256, 256, 0, stream>>>(srcA, dstA, fillptr, epos, srcP);

    for (int l = 0; l < 4; ++l) {
        if (l == 0) {
            gemm_k5<<<Nn, 256, 0, stream>>>(x, Wl[0], bigA);
        } else {
            asplit_k<<<(Nn * HC + 255) / 256, 256, 0, stream>>>(bigB, A2);
            wsplit_k<<<dim3(32, 32), dim3(32, 32), 0, stream>>>(Wl[l], Wt2);
            gemm_mfma<<<dim3(HC / 128, Mpad / 128), 256, 0, stream>>>(A2, Wt2, bigA);
        }
        wae_k<<<1, 64, 0, stream>>>(Wel[l], ael[l], w_ae);
        attn_nodes_k<<<(Nn * Hh) / 4, 256, 0, stream>>>(bigA, asl[l], adl[l], a_srcB, a_dstB);
        alpha_edge_k<<<(En + 255) / 256, 256, 0, stream>>>(srcA, dstA, epos, ea, a_srcB,
                                                           a_dstB, w_ae, alphaP);
        alpha_self_k<<<(Nn + 255) / 256, 256, 0, stream>>>(loop_attr, a_srcB, a_dstB,
                                                           w_ae, alphaSelf);
        aggregate_k<<<(Nn * Hh) / 4, 256, 0, stream>>>(bigA, alphaP, alphaSelf, rowptr,
                                                       srcP, bl[l], bigB, (l == 3) ? 1 : 0);
    }
    mean_heads_k<<<(Nn * Cc) / 256, 256, 0, stream>>>(bigB, bl[3], hfinal);
    pool_k<<<(Nn * Cc) / 256, 256, 0, stream>>>(hfinal, batch, pooled, cntg);
    final_k<<<1, 256, 0, stream>>>(pooled, cntg, lin_w, lin_b, (float*)d_out);
}

// Round 3
// 1142.274 us; speedup vs baseline: 1.7548x; 1.1723x over previous
//
#include <hip/hip_runtime.h>
#include <math.h>

#define Nn 10000
#define En 160000
#define NF 5
#define EF 3
#define Hh 8
#define Cc 128
#define HC 1024
#define Gg 16

#define Mpad 10112   // 79 * 128

typedef __attribute__((ext_vector_type(8))) _Float16 half8;
typedef __attribute__((ext_vector_type(2))) _Float16 half2v;
typedef __attribute__((ext_vector_type(4))) float f32x4;

// ---------------- helpers ----------------

__device__ __forceinline__ void gl_lds16(const void* g, void* l) {
    __builtin_amdgcn_global_load_lds((const __attribute__((address_space(1))) void*)g,
                                     (__attribute__((address_space(3))) void*)l, 16, 0, 0);
}

__device__ __forceinline__ float elu_f(float v) {
    return (v > 0.f) ? v : expm1f(v);
}

// ---------------- preprocessing ----------------

__global__ void deg_sum_k(const int* __restrict__ dst, const float* __restrict__ ea,
                          int* __restrict__ cnt, float* __restrict__ sum_ea) {
    int e = blockIdx.x * 256 + threadIdx.x;
    if (e >= En) return;
    int d = dst[e];
    atomicAdd(&cnt[d], 1);
    atomicAdd(&sum_ea[d * 3 + 0], ea[e * 3 + 0]);
    atomicAdd(&sum_ea[d * 3 + 1], ea[e * 3 + 1]);
    atomicAdd(&sum_ea[d * 3 + 2], ea[e * 3 + 2]);
}

__global__ void finish_loop_k(const int* __restrict__ cnt, float* __restrict__ loop_attr) {
    int n = blockIdx.x * 256 + threadIdx.x;
    if (n >= Nn) return;
    float s = 1.0f / fmaxf((float)cnt[n], 1.0f);
    loop_attr[n * 3 + 0] *= s;
    loop_attr[n * 3 + 1] *= s;
    loop_attr[n * 3 + 2] *= s;
}

__global__ __launch_bounds__(1024) void scan_k(const int* __restrict__ cnt,
                                               int* __restrict__ rowptr,
                                               int* __restrict__ fillptr) {
    __shared__ int sh[1024];
    int tid = threadIdx.x;
    int base = 0;
    for (int chunk = 0; chunk < Nn; chunk += 1024) {
        int i = chunk + tid;
        int v = (i < Nn) ? cnt[i] : 0;
        sh[tid] = v;
        __syncthreads();
        for (int off = 1; off < 1024; off <<= 1) {
            int t = (tid >= off) ? sh[tid - off] : 0;
            __syncthreads();
            sh[tid] += t;
            __syncthreads();
        }
        int excl = sh[tid] - v;
        if (i < Nn) { rowptr[i] = base + excl; fillptr[i] = base + excl; }
        int total = sh[1023];
        __syncthreads();
        base += total;
    }
    if (tid == 0) rowptr[Nn] = base;
}

__global__ void csr_fill_k(const int* __restrict__ src, const int* __restrict__ dst,
                           int* __restrict__ fillptr, int* __restrict__ epos,
                           int* __restrict__ srcP) {
    int e = blockIdx.x * 256 + threadIdx.x;
    if (e >= En) return;
    int d = dst[e];
    int pos = atomicAdd(&fillptr[d], 1);
    epos[e] = pos;
    srcP[pos] = src[e];
}

// ---------------- weight prep (once, all layers) ----------------

// w_ae_all[l][f][h] = sum_c We_l[f, h*C+c] * a_e_l[h, c]
__global__ void wae_all_k(const float* __restrict__ We1, const float* __restrict__ ae1,
                          const float* __restrict__ We2, const float* __restrict__ ae2,
                          const float* __restrict__ We3, const float* __restrict__ ae3,
                          const float* __restrict__ We4, const float* __restrict__ ae4,
                          float* __restrict__ w_ae_all) {
    int t = threadIdx.x;
    if (t >= 96) return;
    int l = t / 24, idx = t % 24;
    int f = idx >> 3, h = idx & 7;
    const float* We = (l == 0) ? We1 : (l == 1) ? We2 : (l == 2) ? We3 : We4;
    const float* ae = (l == 0) ? ae1 : (l == 1) ? ae2 : (l == 2) ? ae3 : ae4;
    float s = 0.f;
    for (int c = 0; c < Cc; ++c) s += We[f * HC + h * Cc + c] * ae[h * Cc + c];
    w_ae_all[l * 24 + f * 8 + h] = s;
}

// W[1024][1024] fp32 -> Wt16[l][n][k] fp16 transposed, for layers 2..4
__global__ __launch_bounds__(1024) void wsplit_all_k(const float* __restrict__ W2,
                                                     const float* __restrict__ W3,
                                                     const float* __restrict__ W4,
                                                     _Float16* __restrict__ Wt16) {
    __shared__ float tile[32][33];
    int z = blockIdx.z;
    const float* W = (z == 0) ? W2 : (z == 1) ? W3 : W4;
    int nb = blockIdx.x * 32, kb = blockIdx.y * 32;
    tile[threadIdx.y][threadIdx.x] = W[(size_t)(kb + threadIdx.y) * HC + nb + threadIdx.x];
    __syncthreads();
    float x = tile[threadIdx.x][threadIdx.y];   // W[kb+tx][nb+ty]
    int n = nb + threadIdx.y, k = kb + threadIdx.x;
    Wt16[(size_t)z * HC * HC + (size_t)n * HC + k] = (_Float16)x;
}

// ---------------- GEMMs ----------------

// layer-1: K=5 tiny GEMM -> fp16 xl
__global__ void gemm_k5(const float* __restrict__ x, const float* __restrict__ Wm,
                        _Float16* __restrict__ out16) {
    int n = blockIdx.x;
    int tid = threadIdx.x;
    __shared__ float xr[8];
    if (tid < NF) xr[tid] = x[n * NF + tid];
    __syncthreads();
    float x0 = xr[0], x1 = xr[1], x2 = xr[2], x3 = xr[3], x4 = xr[4];
    for (int j = tid; j < HC; j += 256) {
        float v = x0 * Wm[j] + x1 * Wm[HC + j] + x2 * Wm[2 * HC + j]
                + x3 * Wm[3 * HC + j] + x4 * Wm[4 * HC + j];
        out16[(size_t)n * HC + j] = (_Float16)v;
    }
}

// fp16 MFMA GEMM, 2-term split on A only:
// C = (A_hi + A_lo) * W,  A2:[Mpad][2048] fp16 (hi|lo along k), Bt:[1024][1024] fp16 (n-major)
// B tile staged once per k-step, used by both A terms.
__global__ __launch_bounds__(256) void gemm_mfma(const _Float16* __restrict__ A2,
                                                 const _Float16* __restrict__ Bt,
                                                 _Float16* __restrict__ C16) {
    __shared__ _Float16 Ah[128 * 32];
    __shared__ _Float16 Al[128 * 32];
    __shared__ _Float16 Bs[128 * 32];
    int tid = threadIdx.x;
    int wave = tid >> 6, lane = tid & 63;
    int wr = wave >> 1, wc = wave & 1;
    int row0 = blockIdx.y * 128;
    int col0 = blockIdx.x * 128;

    f32x4 acc[4][4];
#pragma unroll
    for (int i = 0; i < 4; ++i)
#pragma unroll
        for (int j = 0; j < 4; ++j) acc[i][j] = (f32x4){0.f, 0.f, 0.f, 0.f};

    int srow = lane >> 2;          // 0..15
    int scol = (lane & 3) * 8;     // fp16 index within 32-wide k-tile
    int fr = lane & 15;
    int fk = (lane >> 4) * 8;

    for (int kb = 0; kb < 1024; kb += 32) {
#pragma unroll
        for (int cc = 0; cc < 2; ++cc) {
            int c = wave + cc * 4;
            int r = c * 16 + srow;
            gl_lds16(A2 + (size_t)(row0 + r) * 2048 + kb + scol, &Ah[c * 512 + lane * 8]);
            gl_lds16(A2 + (size_t)(row0 + r) * 2048 + 1024 + kb + scol, &Al[c * 512 + lane * 8]);
            gl_lds16(Bt + (size_t)(col0 + r) * 1024 + kb + scol, &Bs[c * 512 + lane * 8]);
        }
        __syncthreads();

        half8 ah[4], al[4], bf[4];
#pragma unroll
        for (int i = 0; i < 4; ++i) {
            ah[i] = *(const half8*)&Ah[(wr * 64 + i * 16 + fr) * 32 + fk];
            al[i] = *(const half8*)&Al[(wr * 64 + i * 16 + fr) * 32 + fk];
        }
#pragma unroll
        for (int j = 0; j < 4; ++j)
            bf[j] = *(const half8*)&Bs[(wc * 64 + j * 16 + fr) * 32 + fk];
#pragma unroll
        for (int i = 0; i < 4; ++i)
#pragma unroll
            for (int j = 0; j < 4; ++j) {
                acc[i][j] = __builtin_amdgcn_mfma_f32_16x16x32_f16(ah[i], bf[j], acc[i][j],
                                                                   0, 0, 0);
                acc[i][j] = __builtin_amdgcn_mfma_f32_16x16x32_f16(al[i], bf[j], acc[i][j],
                                                                   0, 0, 0);
            }
        __syncthreads();
    }

    // C/D layout: col = lane&15, row = (lane>>4)*4 + reg
    int cn = lane & 15, rq = (lane >> 4) * 4;
#pragma unroll
    for (int i = 0; i < 4; ++i) {
        int rbase = row0 + wr * 64 + i * 16 + rq;
#pragma unroll
        for (int j = 0; j < 4; ++j) {
            int col = col0 + wc * 64 + j * 16 + cn;
#pragma unroll
            for (int r = 0; r < 4; ++r) {
                int row = rbase + r;
                if (row < Nn) C16[(size_t)row * HC + col] = (_Float16)acc[i][j][r];
            }
        }
    }
}

// ---------------- attention ----------------

// one wave per (n,h): a_src, a_dst dots over fp16 xl
__global__ __launch_bounds__(256) void attn_nodes_k(const _Float16* __restrict__ xl16,
                                                    const float* __restrict__ a_s,
                                                    const float* __restrict__ a_d,
                                                    float* __restrict__ a_src,
                                                    float* __restrict__ a_dst) {
    int wid = (blockIdx.x * 256 + threadIdx.x) >> 6;
    int lane = threadIdx.x & 63;
    if (wid >= Nn * Hh) return;
    int n = wid >> 3, h = wid & 7;
    const _Float16* row = xl16 + (size_t)n * HC + h * Cc;
    half2v rv = *(const half2v*)&row[lane * 2];
    float c0 = (float)rv[0], c1 = (float)rv[1];
    float2 sv = *(const float2*)&a_s[h * Cc + lane * 2];
    float2 dv = *(const float2*)&a_d[h * Cc + lane * 2];
    float s1 = c0 * sv.x + c1 * sv.y;
    float s2 = c0 * dv.x + c1 * dv.y;
#pragma unroll
    for (int off = 32; off; off >>= 1) {
        s1 += __shfl_xor(s1, off);
        s2 += __shfl_xor(s2, off);
    }
    if (lane == 0) { a_src[wid] = s1; a_dst[wid] = s2; }
}

// per-edge alpha (leaky-relu), written in CSR-position order
__global__ void alpha_edge_k(const int* __restrict__ src, const int* __restrict__ dst,
                             const int* __restrict__ epos, const float* __restrict__ ea,
                             const float* __restrict__ a_src, const float* __restrict__ a_dst,
                             const float* __restrict__ w_ae, float* __restrict__ alphaP) {
    int e = blockIdx.x * 256 + threadIdx.x;
    if (e >= En) return;
    int s = src[e], d = dst[e];
    int pos = epos[e];
    float f0 = ea[e * 3 + 0], f1 = ea[e * 3 + 1], f2 = ea[e * 3 + 2];
#pragma unroll
    for (int h = 0; h < Hh; ++h) {
        float v = a_src[s * Hh + h] + a_dst[d * Hh + h]
                + f0 * w_ae[h] + f1 * w_ae[Hh + h] + f2 * w_ae[2 * Hh + h];
        alphaP[(size_t)pos * Hh + h] = (v > 0.f) ? v : 0.2f * v;
    }
}

// one wave per (n,h): self-alpha inline, online softmax, fp16 gather.
// mode 0: out = elu(agg + bias) split to fp16 hi/lo into A2 (for next GEMM)
// mode 1: out = raw fp32 into bigB (layer 4)
__global__ __launch_bounds__(256) void aggregate_k(const _Float16* __restrict__ xl16,
                                                   const float* __restrict__ alphaP,
                                                   const float* __restrict__ loop_attr,
                                                   const float* __restrict__ a_srcB,
                                                   const float* __restrict__ a_dstB,
                                                   const float* __restrict__ w_ae,
                                                   const int* __restrict__ rowptr,
                                                   const int* __restrict__ srcP,
                                                   const float* __restrict__ bias,
                                                   _Float16* __restrict__ A2,
                                                   float* __restrict__ bigB,
                                                   int raw_mode) {
    int wid = (blockIdx.x * 256 + threadIdx.x) >> 6;
    int lane = threadIdx.x & 63;
    if (wid >= Nn * Hh) return;
    int n = wid >> 3, h = wid & 7;
    int beg = rowptr[n], end = rowptr[n + 1];

    float f0 = loop_attr[n * 3 + 0], f1 = loop_attr[n * 3 + 1], f2 = loop_attr[n * 3 + 2];
    float av = a_srcB[wid] + a_dstB[wid]
             + f0 * w_ae[h] + f1 * w_ae[Hh + h] + f2 * w_ae[2 * Hh + h];
    float aself = (av > 0.f) ? av : 0.2f * av;

    // online softmax (lane 0 seeds with self term)
    float m = (lane == 0) ? aself : -3.0e38f;
    float s = (lane == 0) ? 1.0f : 0.0f;
    for (int i = beg + lane; i < end; i += 64) {
        float a = alphaP[(size_t)i * Hh + h];
        if (a > m) { s = s * __expf(m - a) + 1.0f; m = a; }
        else s += __expf(a - m);
    }
#pragma unroll
    for (int off = 32; off; off >>= 1) {
        float mo = __shfl_xor(m, off);
        float so = __shfl_xor(s, off);
        float M = fmaxf(m, mo);
        s = s * __expf(m - M) + so * __expf(mo - M);
        m = M;
    }
    float inv = 1.f / (s + 1e-16f);

    const _Float16* xrow = xl16 + (size_t)n * HC + h * Cc;
    float wslf = __expf(aself - m) * inv;
    half2v xv = *(const half2v*)&xrow[lane * 2];
    float acc0 = wslf * (float)xv[0];
    float acc1 = wslf * (float)xv[1];
    for (int i = beg; i < end; ++i) {
        int sn = srcP[i];
        float w = __expf(alphaP[(size_t)i * Hh + h] - m) * inv;
        half2v rv = *(const half2v*)&xl16[(size_t)sn * HC + h * Cc + lane * 2];
        acc0 = fmaf(w, (float)rv[0], acc0);
        acc1 = fmaf(w, (float)rv[1], acc1);
    }

    int ch = h * Cc + lane * 2;
    if (raw_mode) {
        float2 o = make_float2(acc0, acc1);
        *(float2*)&bigB[(size_t)n * HC + ch] = o;
    } else {
        float v0 = elu_f(acc0 + bias[ch]);
        float v1 = elu_f(acc1 + bias[ch + 1]);
        half2v hv; hv[0] = (_Float16)v0; hv[1] = (_Float16)v1;
        float l0 = v0 - (float)hv[0];
        float l1 = v1 - (float)hv[1];
        half2v lv; lv[0] = (_Float16)l0; lv[1] = (_Float16)l1;
        *(half2v*)&A2[(size_t)n * 2048 + ch] = hv;
        *(half2v*)&A2[(size_t)n * 2048 + 1024 + ch] = lv;
    }
}

// layer4 epilogue: mean over heads + bias + elu
__global__ void mean_heads_k(const float* __restrict__ raw, const float* __restrict__ bias,
                             float* __restrict__ hfinal) {
    int idx = blockIdx.x * 256 + threadIdx.x;
    if (idx >= Nn * Cc) return;
    int n = idx >> 7, c = idx & 127;
    float s = 0.f;
#pragma unroll
    for (int h = 0; h < Hh; ++h) s += raw[(size_t)n * HC + h * Cc + c];
    hfinal[idx] = elu_f(s * 0.125f + bias[c]);
}

__global__ void pool_k(const float* __restrict__ hfinal, const int* __restrict__ batch,
                       float* __restrict__ pooled, float* __restrict__ cntg) {
    int idx = blockIdx.x * 256 + threadIdx.x;
    if (idx >= Nn * Cc) return;
    int n = idx >> 7, c = idx & 127;
    int g = batch[n];
    atomicAdd(&pooled[g * Cc + c], hfinal[idx]);
    if (c == 0) atomicAdd(&cntg[g], 1.0f);
}

__global__ void final_k(const float* __restrict__ pooled, const float* __restrict__ cntg,
                        const float* __restrict__ lin_w, const float* __restrict__ lin_b,
                        float* __restrict__ out) {
    int lane = threadIdx.x & 63;
    int w = threadIdx.x >> 6;
    for (int g = w; g < Gg; g += 4) {
        float v = pooled[g * Cc + lane] * lin_w[lane]
                + pooled[g * Cc + lane + 64] * lin_w[lane + 64];
#pragma unroll
        for (int off = 32; off; off >>= 1) v += __shfl_xor(v, off);
        if (lane == 0) out[g] = v / fmaxf(cntg[g], 1.0f) + lin_b[0];
    }
}

// ---------------- launch ----------------

extern "C" void kernel_launch(void* const* d_in, const int* in_sizes, int n_in,
                              void* d_out, int out_size, void* d_ws, size_t ws_size,
                              hipStream_t stream) {
    const float* x = (const float*)d_in[0];
    const int* ei = (const int*)d_in[1];
    const float* ea = (const float*)d_in[2];
    const int* batch = (const int*)d_in[3];
    const float *Wl[4], *Wel[4], *asl[4], *adl[4], *ael[4], *bl[4];
    for (int l = 0; l < 4; ++l) {
        Wl[l] = (const float*)d_in[4 + 6 * l];
        Wel[l] = (const float*)d_in[5 + 6 * l];
        asl[l] = (const float*)d_in[6 + 6 * l];
        adl[l] = (const float*)d_in[7 + 6 * l];
        ael[l] = (const float*)d_in[8 + 6 * l];
        bl[l] = (const float*)d_in[9 + 6 * l];
    }
    const float* lin_w = (const float*)d_in[28];
    const float* lin_b = (const float*)d_in[29];
    const int* srcA = ei;
    const int* dstA = ei + En;

    float* Wp = (float*)d_ws;
    size_t o = 0;
    _Float16* A2 = (_Float16*)(Wp + o); o += (size_t)Mpad * 1024;        // split acts (2048 halves/row)
    _Float16* Wt16 = (_Float16*)(Wp + o); o += (size_t)3 * HC * HC / 2;  // 3 transposed fp16 weights
    _Float16* xl16 = (_Float16*)(Wp + o); o += (size_t)Nn * HC / 2;      // xl fp16
    float* bigB = Wp + o; o += (size_t)Nn * HC;                          // layer-4 raw
    float* alphaP = Wp + o; o += (size_t)En * Hh;
    float* loop_attr = Wp + o; o += Nn * 3;
    int* cnt = (int*)(Wp + o); o += Nn;
    int* rowptr = (int*)(Wp + o); o += Nn + 1;
    int* fillptr = (int*)(Wp + o); o += Nn;
    int* epos = (int*)(Wp + o); o += En;
    int* srcP = (int*)(Wp + o); o += En;
    float* a_srcB = Wp + o; o += Nn * Hh;
    float* a_dstB = Wp + o; o += Nn * Hh;
    float* w_ae_all = Wp + o; o += 128;
    float* hfinal = Wp + o; o += Nn * Cc;
    float* pooled = Wp + o; o += Gg * Cc;
    float* cntg = Wp + o; o += Gg;

    hipMemsetAsync(cnt, 0, Nn * sizeof(int), stream);
    hipMemsetAsync(loop_attr, 0, Nn * 3 * sizeof(float), stream);
    hipMemsetAsync(pooled, 0, (Gg * Cc + Gg) * sizeof(float), stream);

    deg_sum_k<<<(En + 255) / 256, 256, 0, stream>>>(dstA, ea, cnt, loop_attr);
    finish_loop_k<<<(Nn + 255) / 256, 256, 0, stream>>>(cnt, loop_attr);
    scan_k<<<1, 1024, 0, stream>>>(cnt, rowptr, fillptr);
    csr_fill_k<<<(En + 255) / 256, 256, 0, stream>>>(srcA, dstA, fillptr, epos, srcP);
    wae_all_k<<<1, 128, 0, stream>>>(Wel[0], ael[0], Wel[1], ael[1], Wel[2], ael[2],
                                     Wel[3], ael[3], w_ae_all);
    wsplit_all_k<<<dim3(32, 32, 3), dim3(32, 32), 0, stream>>>(Wl[1], Wl[2], Wl[3], Wt16);

    for (int l = 0; l < 4; ++l) {
        if (l == 0)
            gemm_k5<<<Nn, 256, 0, stream>>>(x, Wl[0], xl16);
        else
            gemm_mfma<<<dim3(HC / 128, Mpad / 128), 256, 0, stream>>>(
                A2, Wt16 + (size_t)(l - 1) * HC * HC, xl16);
        attn_nodes_k<<<(Nn * Hh) / 4, 256, 0, stream>>>(xl16, asl[l], adl[l], a_srcB, a_dstB);
        alpha_edge_k<<<(En + 255) / 256, 256, 0, stream>>>(srcA, dstA, epos, ea, a_srcB,
                                                           a_dstB, w_ae_all + l * 24, alphaP);
        aggregate_k<<<(Nn * Hh) / 4, 256, 0, stream>>>(xl16, alphaP, loop_attr, a_srcB,
                                                       a_dstB, w_ae_all + l * 24, rowptr,
                                                       srcP, bl[l], A2, bigB,
                                                       (l == 3) ? 1 : 0);
    }
    mean_heads_k<<<(Nn * Cc) / 256, 256, 0, stream>>>(bigB, bl[3], hfinal);
    pool_k<<<(Nn * Cc) / 256, 256, 0, stream>>>(hfinal, batch, pooled, cntg);
    final_k<<<1, 256, 0, stream>>>(pooled, cntg, lin_w, lin_b, (float*)d_out);
}

// Round 4
// 831.832 us; speedup vs baseline: 2.4097x; 1.3732x over previous
//
#include <hip/hip_runtime.h>
#include <math.h>

#define Nn 10000
#define En 160000
#define NF 5
#define EF 3
#define Hh 8
#define Cc 128
#define HC 1024
#define Gg 16

#define Mpad 10112   // 79 * 128

typedef __attribute__((ext_vector_type(8))) _Float16 half8;
typedef __attribute__((ext_vector_type(2))) _Float16 half2v;
typedef __attribute__((ext_vector_type(4))) float f32x4;

// ---------------- helpers ----------------

__device__ __forceinline__ void gl_lds16(const void* g, void* l) {
    __builtin_amdgcn_global_load_lds((const __attribute__((address_space(1))) void*)g,
                                     (__attribute__((address_space(3))) void*)l, 16, 0, 0);
}

__device__ __forceinline__ float elu_f(float v) {
    return (v > 0.f) ? v : expm1f(v);
}

// ---------------- preprocessing ----------------

__global__ void deg_sum_k(const int* __restrict__ dst, const float* __restrict__ ea,
                          int* __restrict__ cnt, float* __restrict__ sum_ea) {
    int e = blockIdx.x * 256 + threadIdx.x;
    if (e >= En) return;
    int d = dst[e];
    atomicAdd(&cnt[d], 1);
    atomicAdd(&sum_ea[d * 3 + 0], ea[e * 3 + 0]);
    atomicAdd(&sum_ea[d * 3 + 1], ea[e * 3 + 1]);
    atomicAdd(&sum_ea[d * 3 + 2], ea[e * 3 + 2]);
}

__global__ void finish_loop_k(const int* __restrict__ cnt, float* __restrict__ loop_attr) {
    int n = blockIdx.x * 256 + threadIdx.x;
    if (n >= Nn) return;
    float s = 1.0f / fmaxf((float)cnt[n], 1.0f);
    loop_attr[n * 3 + 0] *= s;
    loop_attr[n * 3 + 1] *= s;
    loop_attr[n * 3 + 2] *= s;
}

__global__ __launch_bounds__(1024) void scan_k(const int* __restrict__ cnt,
                                               int* __restrict__ rowptr,
                                               int* __restrict__ fillptr) {
    __shared__ int sh[1024];
    int tid = threadIdx.x;
    int base = 0;
    for (int chunk = 0; chunk < Nn; chunk += 1024) {
        int i = chunk + tid;
        int v = (i < Nn) ? cnt[i] : 0;
        sh[tid] = v;
        __syncthreads();
        for (int off = 1; off < 1024; off <<= 1) {
            int t = (tid >= off) ? sh[tid - off] : 0;
            __syncthreads();
            sh[tid] += t;
            __syncthreads();
        }
        int excl = sh[tid] - v;
        if (i < Nn) { rowptr[i] = base + excl; fillptr[i] = base + excl; }
        int total = sh[1023];
        __syncthreads();
        base += total;
    }
    if (tid == 0) rowptr[Nn] = base;
}

__global__ void csr_fill_k(const int* __restrict__ src, const int* __restrict__ dst,
                           int* __restrict__ fillptr, int* __restrict__ epos,
                           int* __restrict__ srcP) {
    int e = blockIdx.x * 256 + threadIdx.x;
    if (e >= En) return;
    int d = dst[e];
    int pos = atomicAdd(&fillptr[d], 1);
    epos[e] = pos;
    srcP[pos] = src[e];
}

// group boundaries from sorted batch: gstart[g] = first node with batch>=g, gstart[G]=Nn
__global__ void bounds_k(const int* __restrict__ batch, int* __restrict__ gstart) {
    int i = blockIdx.x * 256 + threadIdx.x;
    if (i >= Nn) return;
    int b = batch[i];
    if (i == 0) {
        for (int g = 0; g <= b; ++g) gstart[g] = 0;
    } else {
        int pb = batch[i - 1];
        for (int g = pb + 1; g <= b; ++g) gstart[g] = i;
    }
    if (i == Nn - 1) {
        for (int g = b + 1; g <= Gg; ++g) gstart[g] = Nn;
    }
}

// ---------------- weight prep (once, all layers) ----------------

__global__ void wae_all_k(const float* __restrict__ We1, const float* __restrict__ ae1,
                          const float* __restrict__ We2, const float* __restrict__ ae2,
                          const float* __restrict__ We3, const float* __restrict__ ae3,
                          const float* __restrict__ We4, const float* __restrict__ ae4,
                          float* __restrict__ w_ae_all) {
    int t = threadIdx.x;
    if (t >= 96) return;
    int l = t / 24, idx = t % 24;
    int f = idx >> 3, h = idx & 7;
    const float* We = (l == 0) ? We1 : (l == 1) ? We2 : (l == 2) ? We3 : We4;
    const float* ae = (l == 0) ? ae1 : (l == 1) ? ae2 : (l == 2) ? ae3 : ae4;
    float s = 0.f;
    for (int c = 0; c < Cc; ++c) s += We[f * HC + h * Cc + c] * ae[h * Cc + c];
    w_ae_all[l * 24 + f * 8 + h] = s;
}

__global__ __launch_bounds__(1024) void wsplit_all_k(const float* __restrict__ W2,
                                                     const float* __restrict__ W3,
                                                     const float* __restrict__ W4,
                                                     _Float16* __restrict__ Wt16) {
    __shared__ float tile[32][33];
    int z = blockIdx.z;
    const float* W = (z == 0) ? W2 : (z == 1) ? W3 : W4;
    int nb = blockIdx.x * 32, kb = blockIdx.y * 32;
    tile[threadIdx.y][threadIdx.x] = W[(size_t)(kb + threadIdx.y) * HC + nb + threadIdx.x];
    __syncthreads();
    float x = tile[threadIdx.x][threadIdx.y];   // W[kb+tx][nb+ty]
    int n = nb + threadIdx.y, k = kb + threadIdx.x;
    Wt16[(size_t)z * HC * HC + (size_t)n * HC + k] = (_Float16)x;
}

// ---------------- GEMMs ----------------

__global__ void gemm_k5(const float* __restrict__ x, const float* __restrict__ Wm,
                        _Float16* __restrict__ out16) {
    int n = blockIdx.x;
    int tid = threadIdx.x;
    __shared__ float xr[8];
    if (tid < NF) xr[tid] = x[n * NF + tid];
    __syncthreads();
    float x0 = xr[0], x1 = xr[1], x2 = xr[2], x3 = xr[3], x4 = xr[4];
    for (int j = tid; j < HC; j += 256) {
        float v = x0 * Wm[j] + x1 * Wm[HC + j] + x2 * Wm[2 * HC + j]
                + x3 * Wm[3 * HC + j] + x4 * Wm[4 * HC + j];
        out16[(size_t)n * HC + j] = (_Float16)v;
    }
}

// fp16 MFMA GEMM, 2-term split on A only: C = (A_hi + A_lo) * W
__global__ __launch_bounds__(256) void gemm_mfma(const _Float16* __restrict__ A2,
                                                 const _Float16* __restrict__ Bt,
                                                 _Float16* __restrict__ C16) {
    __shared__ _Float16 Ah[128 * 32];
    __shared__ _Float16 Al[128 * 32];
    __shared__ _Float16 Bs[128 * 32];
    int tid = threadIdx.x;
    int wave = tid >> 6, lane = tid & 63;
    int wr = wave >> 1, wc = wave & 1;
    int row0 = blockIdx.y * 128;
    int col0 = blockIdx.x * 128;

    f32x4 acc[4][4];
#pragma unroll
    for (int i = 0; i < 4; ++i)
#pragma unroll
        for (int j = 0; j < 4; ++j) acc[i][j] = (f32x4){0.f, 0.f, 0.f, 0.f};

    int srow = lane >> 2;
    int scol = (lane & 3) * 8;
    int fr = lane & 15;
    int fk = (lane >> 4) * 8;

    for (int kb = 0; kb < 1024; kb += 32) {
#pragma unroll
        for (int cc = 0; cc < 2; ++cc) {
            int c = wave + cc * 4;
            int r = c * 16 + srow;
            gl_lds16(A2 + (size_t)(row0 + r) * 2048 + kb + scol, &Ah[c * 512 + lane * 8]);
            gl_lds16(A2 + (size_t)(row0 + r) * 2048 + 1024 + kb + scol, &Al[c * 512 + lane * 8]);
            gl_lds16(Bt + (size_t)(col0 + r) * 1024 + kb + scol, &Bs[c * 512 + lane * 8]);
        }
        __syncthreads();

        half8 ah[4], al[4], bf[4];
#pragma unroll
        for (int i = 0; i < 4; ++i) {
            ah[i] = *(const half8*)&Ah[(wr * 64 + i * 16 + fr) * 32 + fk];
            al[i] = *(const half8*)&Al[(wr * 64 + i * 16 + fr) * 32 + fk];
        }
#pragma unroll
        for (int j = 0; j < 4; ++j)
            bf[j] = *(const half8*)&Bs[(wc * 64 + j * 16 + fr) * 32 + fk];
#pragma unroll
        for (int i = 0; i < 4; ++i)
#pragma unroll
            for (int j = 0; j < 4; ++j) {
                acc[i][j] = __builtin_amdgcn_mfma_f32_16x16x32_f16(ah[i], bf[j], acc[i][j],
                                                                   0, 0, 0);
                acc[i][j] = __builtin_amdgcn_mfma_f32_16x16x32_f16(al[i], bf[j], acc[i][j],
                                                                   0, 0, 0);
            }
        __syncthreads();
    }

    int cn = lane & 15, rq = (lane >> 4) * 4;
#pragma unroll
    for (int i = 0; i < 4; ++i) {
        int rbase = row0 + wr * 64 + i * 16 + rq;
#pragma unroll
        for (int j = 0; j < 4; ++j) {
            int col = col0 + wc * 64 + j * 16 + cn;
#pragma unroll
            for (int r = 0; r < 4; ++r) {
                int row = rbase + r;
                if (row < Nn) C16[(size_t)row * HC + col] = (_Float16)acc[i][j][r];
            }
        }
    }
}

// ---------------- attention ----------------

__global__ __launch_bounds__(256) void attn_nodes_k(const _Float16* __restrict__ xl16,
                                                    const float* __restrict__ a_s,
                                                    const float* __restrict__ a_d,
                                                    float* __restrict__ a_src,
                                                    float* __restrict__ a_dst) {
    int wid = (blockIdx.x * 256 + threadIdx.x) >> 6;
    int lane = threadIdx.x & 63;
    if (wid >= Nn * Hh) return;
    int n = wid >> 3, h = wid & 7;
    const _Float16* row = xl16 + (size_t)n * HC + h * Cc;
    half2v rv = *(const half2v*)&row[lane * 2];
    float c0 = (float)rv[0], c1 = (float)rv[1];
    float2 sv = *(const float2*)&a_s[h * Cc + lane * 2];
    float2 dv = *(const float2*)&a_d[h * Cc + lane * 2];
    float s1 = c0 * sv.x + c1 * sv.y;
    float s2 = c0 * dv.x + c1 * dv.y;
#pragma unroll
    for (int off = 32; off; off >>= 1) {
        s1 += __shfl_xor(s1, off);
        s2 += __shfl_xor(s2, off);
    }
    if (lane == 0) { a_src[wid] = s1; a_dst[wid] = s2; }
}

__global__ void alpha_edge_k(const int* __restrict__ src, const int* __restrict__ dst,
                             const int* __restrict__ epos, const float* __restrict__ ea,
                             const float* __restrict__ a_src, const float* __restrict__ a_dst,
                             const float* __restrict__ w_ae, float* __restrict__ alphaP) {
    int e = blockIdx.x * 256 + threadIdx.x;
    if (e >= En) return;
    int s = src[e], d = dst[e];
    int pos = epos[e];
    float f0 = ea[e * 3 + 0], f1 = ea[e * 3 + 1], f2 = ea[e * 3 + 2];
#pragma unroll
    for (int h = 0; h < Hh; ++h) {
        float v = a_src[s * Hh + h] + a_dst[d * Hh + h]
                + f0 * w_ae[h] + f1 * w_ae[Hh + h] + f2 * w_ae[2 * Hh + h];
        alphaP[(size_t)pos * Hh + h] = (v > 0.f) ? v : 0.2f * v;
    }
}

// ONE WAVE PER NODE, all 8 heads.
// lane t: phase-1 head = t&7 (slot t>>3 strides edges); phase-2 channels = halfs [t*16, t*16+16),
// i.e. head t>>3, within-head channel (t&7)*16 + j.
// mode 0: out = elu(agg+bias) -> fp16 hi/lo into A2 (next GEMM input)
// mode 1: head-mean + bias + elu -> hfinal[n][128]
__global__ __launch_bounds__(256) void aggregate_k(const _Float16* __restrict__ xl16,
                                                   const float* __restrict__ alphaP,
                                                   const float* __restrict__ loop_attr,
                                                   const float* __restrict__ a_srcB,
                                                   const float* __restrict__ a_dstB,
                                                   const float* __restrict__ w_ae,
                                                   const int* __restrict__ rowptr,
                                                   const int* __restrict__ srcP,
                                                   const float* __restrict__ bias,
                                                   _Float16* __restrict__ A2,
                                                   float* __restrict__ hfinal,
                                                   int raw_mode) {
    int n = (blockIdx.x * 256 + threadIdx.x) >> 6;
    int lane = threadIdx.x & 63;
    if (n >= Nn) return;
    int beg = rowptr[n], end = rowptr[n + 1];
    int hh = lane & 7;      // phase-1 head
    int slot = lane >> 3;
    int hc = lane >> 3;     // phase-2 head (channel block)

    // self alpha for head hh
    float f0 = loop_attr[n * 3 + 0], f1 = loop_attr[n * 3 + 1], f2 = loop_attr[n * 3 + 2];
    float av = a_srcB[n * 8 + hh] + a_dstB[n * 8 + hh]
             + f0 * w_ae[hh] + f1 * w_ae[8 + hh] + f2 * w_ae[16 + hh];
    float aself = (av > 0.f) ? av : 0.2f * av;

    // phase 1: online softmax stats, 8 edges x 8 heads per sweep
    float m = (slot == 0) ? aself : -3.0e38f;
    float s = (slot == 0) ? 1.0f : 0.0f;
    for (int i = beg + slot; i < end; i += 8) {
        float a = alphaP[(size_t)i * 8 + hh];
        if (a > m) { s = s * __expf(m - a) + 1.0f; m = a; }
        else s += __expf(a - m);
    }
#pragma unroll
    for (int off = 8; off < 64; off <<= 1) {
        float mo = __shfl_xor(m, off);
        float so = __shfl_xor(s, off);
        float M = fmaxf(m, mo);
        s = s * __expf(m - M) + so * __expf(mo - M);
        m = M;
    }
    float inv = 1.f / (s + 1e-16f);
    float wself = __expf(aself - m) * inv;   // meaningful per head lane&7

    // re-map stats to channel head hc (lane hc in 0..7 holds head hc)
    float m_c = __shfl(m, hc);
    float inv_c = __shfl(inv, hc);
    float wself_c = __shfl(wself, hc);

    // phase 2: gather. lane reads halfs [lane*16, lane*16+16)
    float acc[16];
    {
        const _Float16* r = xl16 + (size_t)n * HC + lane * 16;
        half8 r0 = *(const half8*)r;
        half8 r1 = *(const half8*)(r + 8);
#pragma unroll
        for (int j = 0; j < 8; ++j) {
            acc[j] = wself_c * (float)r0[j];
            acc[8 + j] = wself_c * (float)r1[j];
        }
    }
    for (int i = beg; i < end; ++i) {
        float a = alphaP[(size_t)i * 8 + hc];
        float w = __expf(a - m_c) * inv_c;
        int sn = srcP[i];
        const _Float16* r = xl16 + (size_t)sn * HC + lane * 16;
        half8 r0 = *(const half8*)r;
        half8 r1 = *(const half8*)(r + 8);
#pragma unroll
        for (int j = 0; j < 8; ++j) {
            acc[j] = fmaf(w, (float)r0[j], acc[j]);
            acc[8 + j] = fmaf(w, (float)r1[j], acc[8 + j]);
        }
    }

    if (!raw_mode) {
        int ch = lane * 16;
        half8 hv0, hv1, lv0, lv1;
#pragma unroll
        for (int j = 0; j < 8; ++j) {
            float v = elu_f(acc[j] + bias[ch + j]);
            hv0[j] = (_Float16)v;
            lv0[j] = (_Float16)(v - (float)hv0[j]);
            float v2 = elu_f(acc[8 + j] + bias[ch + 8 + j]);
            hv1[j] = (_Float16)v2;
            lv1[j] = (_Float16)(v2 - (float)hv1[j]);
        }
        _Float16* p = A2 + (size_t)n * 2048 + ch;
        *(half8*)p = hv0;
        *(half8*)(p + 8) = hv1;
        *(half8*)(p + 1024) = lv0;
        *(half8*)(p + 1032) = lv1;
    } else {
        // head-mean: sum over lanes with same (lane&7)
#pragma unroll
        for (int off = 8; off < 64; off <<= 1)
#pragma unroll
            for (int j = 0; j < 16; ++j) acc[j] += __shfl_xor(acc[j], off);
        if (lane < 8) {
            int c0 = lane * 16;
#pragma unroll
            for (int j = 0; j < 16; ++j) {
                float v = elu_f(acc[j] * 0.125f + bias[c0 + j]);
                hfinal[(size_t)n * Cc + c0 + j] = v;
            }
        }
    }
}

// ---------------- pooling + final linear (fused, no atomics) ----------------

__global__ __launch_bounds__(256) void pool_final_k(const float* __restrict__ hfinal,
                                                    const int* __restrict__ gstart,
                                                    const float* __restrict__ lin_w,
                                                    const float* __restrict__ lin_b,
                                                    float* __restrict__ out) {
    __shared__ float sh[256];
    int g = blockIdx.x;
    int tid = threadIdx.x;
    int c = tid & 127, half = tid >> 7;
    int s = gstart[g], e = gstart[g + 1];
    float acc = 0.f;
    for (int n = s + half; n < e; n += 2) acc += hfinal[(size_t)n * Cc + c];
    sh[tid] = acc * lin_w[c];
    __syncthreads();
    for (int off = 128; off; off >>= 1) {
        if (tid < off) sh[tid] += sh[tid + off];
        __syncthreads();
    }
    if (tid == 0) out[g] = sh[0] / fmaxf((float)(e - s), 1.f) + lin_b[0];
}

// ---------------- launch ----------------

extern "C" void kernel_launch(void* const* d_in, const int* in_sizes, int n_in,
                              void* d_out, int out_size, void* d_ws, size_t ws_size,
                              hipStream_t stream) {
    const float* x = (const float*)d_in[0];
    const int* ei = (const int*)d_in[1];
    const float* ea = (const float*)d_in[2];
    const int* batch = (const int*)d_in[3];
    const float *Wl[4], *Wel[4], *asl[4], *adl[4], *ael[4], *bl[4];
    for (int l = 0; l < 4; ++l) {
        Wl[l] = (const float*)d_in[4 + 6 * l];
        Wel[l] = (const float*)d_in[5 + 6 * l];
        asl[l] = (const float*)d_in[6 + 6 * l];
        adl[l] = (const float*)d_in[7 + 6 * l];
        ael[l] = (const float*)d_in[8 + 6 * l];
        bl[l] = (const float*)d_in[9 + 6 * l];
    }
    const float* lin_w = (const float*)d_in[28];
    const float* lin_b = (const float*)d_in[29];
    const int* srcA = ei;
    const int* dstA = ei + En;

    float* Wp = (float*)d_ws;
    size_t o = 0;
    _Float16* A2 = (_Float16*)(Wp + o); o += (size_t)Mpad * 1024;        // split acts
    _Float16* Wt16 = (_Float16*)(Wp + o); o += (size_t)3 * HC * HC / 2;  // 3 fp16 W^T
    _Float16* xl16 = (_Float16*)(Wp + o); o += (size_t)Nn * HC / 2;      // xl fp16
    float* alphaP = Wp + o; o += (size_t)En * Hh;
    float* loop_attr = Wp + o; o += Nn * 3;
    int* cnt = (int*)(Wp + o); o += Nn;
    int* rowptr = (int*)(Wp + o); o += Nn + 1;
    int* fillptr = (int*)(Wp + o); o += Nn;
    int* epos = (int*)(Wp + o); o += En;
    int* srcP = (int*)(Wp + o); o += En;
    int* gstart = (int*)(Wp + o); o += Gg + 1;
    float* a_srcB = Wp + o; o += Nn * Hh;
    float* a_dstB = Wp + o; o += Nn * Hh;
    float* w_ae_all = Wp + o; o += 128;
    float* hfinal = Wp + o; o += Nn * Cc;

    hipMemsetAsync(cnt, 0, Nn * sizeof(int), stream);
    hipMemsetAsync(loop_attr, 0, Nn * 3 * sizeof(float), stream);

    deg_sum_k<<<(En + 255) / 256, 256, 0, stream>>>(dstA, ea, cnt, loop_attr);
    finish_loop_k<<<(Nn + 255) / 256, 256, 0, stream>>>(cnt, loop_attr);
    scan_k<<<1, 1024, 0, stream>>>(cnt, rowptr, fillptr);
    csr_fill_k<<<(En + 255) / 256, 256, 0, stream>>>(srcA, dstA, fillptr, epos, srcP);
    bounds_k<<<(Nn + 255) / 256, 256, 0, stream>>>(batch, gstart);
    wae_all_k<<<1, 128, 0, stream>>>(Wel[0], ael[0], Wel[1], ael[1], Wel[2], ael[2],
                                     Wel[3], ael[3], w_ae_all);
    wsplit_all_k<<<dim3(32, 32, 3), dim3(32, 32), 0, stream>>>(Wl[1], Wl[2], Wl[3], Wt16);

    for (int l = 0; l < 4; ++l) {
        if (l == 0)
            gemm_k5<<<Nn, 256, 0, stream>>>(x, Wl[0], xl16);
        else
            gemm_mfma<<<dim3(HC / 128, Mpad / 128), 256, 0, stream>>>(
                A2, Wt16 + (size_t)(l - 1) * HC * HC, xl16);
        attn_nodes_k<<<(Nn * Hh) / 4, 256, 0, stream>>>(xl16, asl[l], adl[l], a_srcB, a_dstB);
        alpha_edge_k<<<(En + 255) / 256, 256, 0, stream>>>(srcA, dstA, epos, ea, a_srcB,
                                                           a_dstB, w_ae_all + l * 24, alphaP);
        aggregate_k<<<(Nn + 3) / 4, 256, 0, stream>>>(xl16, alphaP, loop_attr, a_srcB,
                                                      a_dstB, w_ae_all + l * 24, rowptr,
                                                      srcP, bl[l], A2, hfinal,
                                                      (l == 3) ? 1 : 0);
    }
    pool_final_k<<<Gg, 256, 0, stream>>>(hfinal, gstart, lin_w, lin_b, (float*)d_out);
}

// Round 5
// 652.163 us; speedup vs baseline: 3.0736x; 1.2755x over previous
//
#include <hip/hip_runtime.h>
#include <math.h>

#define Nn 10000
#define En 160000
#define NF 5
#define EF 3
#define Hh 8
#define Cc 128
#define HC 1024
#define Gg 16

#define Mpad 10112   // 79 * 128

typedef __attribute__((ext_vector_type(8))) _Float16 half8;
typedef __attribute__((ext_vector_type(4))) float f32x4;

// ---------------- helpers ----------------

__device__ __forceinline__ void gl_lds16(const void* g, void* l) {
    __builtin_amdgcn_global_load_lds((const __attribute__((address_space(1))) void*)g,
                                     (__attribute__((address_space(3))) void*)l, 16, 0, 0);
}

__device__ __forceinline__ float elu_f(float v) {
    return (v > 0.f) ? v : expm1f(v);
}

// ---------------- preprocessing ----------------

__global__ void deg_sum_k(const int* __restrict__ dst, const float* __restrict__ ea,
                          int* __restrict__ cnt, float* __restrict__ sum_ea) {
    int e = blockIdx.x * 256 + threadIdx.x;
    if (e >= En) return;
    int d = dst[e];
    atomicAdd(&cnt[d], 1);
    atomicAdd(&sum_ea[d * 3 + 0], ea[e * 3 + 0]);
    atomicAdd(&sum_ea[d * 3 + 1], ea[e * 3 + 1]);
    atomicAdd(&sum_ea[d * 3 + 2], ea[e * 3 + 2]);
}

__global__ void finish_loop_k(const int* __restrict__ cnt, float* __restrict__ loop_attr) {
    int n = blockIdx.x * 256 + threadIdx.x;
    if (n >= Nn) return;
    float s = 1.0f / fmaxf((float)cnt[n], 1.0f);
    loop_attr[n * 3 + 0] *= s;
    loop_attr[n * 3 + 1] *= s;
    loop_attr[n * 3 + 2] *= s;
}

__global__ __launch_bounds__(1024) void scan_k(const int* __restrict__ cnt,
                                               int* __restrict__ rowptr,
                                               int* __restrict__ fillptr) {
    __shared__ int sh[1024];
    int tid = threadIdx.x;
    int base = 0;
    for (int chunk = 0; chunk < Nn; chunk += 1024) {
        int i = chunk + tid;
        int v = (i < Nn) ? cnt[i] : 0;
        sh[tid] = v;
        __syncthreads();
        for (int off = 1; off < 1024; off <<= 1) {
            int t = (tid >= off) ? sh[tid - off] : 0;
            __syncthreads();
            sh[tid] += t;
            __syncthreads();
        }
        int excl = sh[tid] - v;
        if (i < Nn) { rowptr[i] = base + excl; fillptr[i] = base + excl; }
        int total = sh[1023];
        __syncthreads();
        base += total;
    }
    if (tid == 0) rowptr[Nn] = base;
}

__global__ void csr_fill_k(const int* __restrict__ src, const int* __restrict__ dst,
                           int* __restrict__ fillptr, int* __restrict__ epos,
                           int* __restrict__ srcP) {
    int e = blockIdx.x * 256 + threadIdx.x;
    if (e >= En) return;
    int d = dst[e];
    int pos = atomicAdd(&fillptr[d], 1);
    epos[e] = pos;
    srcP[pos] = src[e];
}

// group boundaries from sorted batch
__global__ void bounds_k(const int* __restrict__ batch, int* __restrict__ gstart) {
    int i = blockIdx.x * 256 + threadIdx.x;
    if (i >= Nn) return;
    int b = batch[i];
    if (i == 0) {
        for (int g = 0; g <= b; ++g) gstart[g] = 0;
    } else {
        int pb = batch[i - 1];
        for (int g = pb + 1; g <= b; ++g) gstart[g] = i;
    }
    if (i == Nn - 1) {
        for (int g = b + 1; g <= Gg; ++g) gstart[g] = Nn;
    }
}

// ---------------- weight prep (once, all layers) ----------------

__global__ void wae_all_k(const float* __restrict__ We1, const float* __restrict__ ae1,
                          const float* __restrict__ We2, const float* __restrict__ ae2,
                          const float* __restrict__ We3, const float* __restrict__ ae3,
                          const float* __restrict__ We4, const float* __restrict__ ae4,
                          float* __restrict__ w_ae_all) {
    int t = threadIdx.x;
    if (t >= 96) return;
    int l = t / 24, idx = t % 24;
    int f = idx >> 3, h = idx & 7;
    const float* We = (l == 0) ? We1 : (l == 1) ? We2 : (l == 2) ? We3 : We4;
    const float* ae = (l == 0) ? ae1 : (l == 1) ? ae2 : (l == 2) ? ae3 : ae4;
    float s = 0.f;
    for (int c = 0; c < Cc; ++c) s += We[f * HC + h * Cc + c] * ae[h * Cc + c];
    w_ae_all[l * 24 + f * 8 + h] = s;
}

__global__ __launch_bounds__(1024) void wsplit_all_k(const float* __restrict__ W2,
                                                     const float* __restrict__ W3,
                                                     const float* __restrict__ W4,
                                                     _Float16* __restrict__ Wt16) {
    __shared__ float tile[32][33];
    int z = blockIdx.z;
    const float* W = (z == 0) ? W2 : (z == 1) ? W3 : W4;
    int nb = blockIdx.x * 32, kb = blockIdx.y * 32;
    tile[threadIdx.y][threadIdx.x] = W[(size_t)(kb + threadIdx.y) * HC + nb + threadIdx.x];
    __syncthreads();
    float x = tile[threadIdx.x][threadIdx.y];   // W[kb+tx][nb+ty]
    int n = nb + threadIdx.y, k = kb + threadIdx.x;
    Wt16[(size_t)z * HC * HC + (size_t)n * HC + k] = (_Float16)x;
}

// ---------------- GEMMs ----------------

__global__ void gemm_k5(const float* __restrict__ x, const float* __restrict__ Wm,
                        _Float16* __restrict__ out16) {
    int n = blockIdx.x;
    int tid = threadIdx.x;
    __shared__ float xr[8];
    if (tid < NF) xr[tid] = x[n * NF + tid];
    __syncthreads();
    float x0 = xr[0], x1 = xr[1], x2 = xr[2], x3 = xr[3], x4 = xr[4];
    for (int j = tid; j < HC; j += 256) {
        float v = x0 * Wm[j] + x1 * Wm[HC + j] + x2 * Wm[2 * HC + j]
                + x3 * Wm[3 * HC + j] + x4 * Wm[4 * HC + j];
        out16[(size_t)n * HC + j] = (_Float16)v;
    }
}

// pure fp16 MFMA GEMM: C16 = A * W^T-tiles (m97 structure, 16 KB LDS)
__global__ __launch_bounds__(256) void gemm_mfma(const _Float16* __restrict__ A,
                                                 const _Float16* __restrict__ Bt,
                                                 _Float16* __restrict__ C16) {
    __shared__ _Float16 As[128 * 32];
    __shared__ _Float16 Bs[128 * 32];
    int tid = threadIdx.x;
    int wave = tid >> 6, lane = tid & 63;
    int wr = wave >> 1, wc = wave & 1;
    int row0 = blockIdx.y * 128;
    int col0 = blockIdx.x * 128;

    f32x4 acc[4][4];
#pragma unroll
    for (int i = 0; i < 4; ++i)
#pragma unroll
        for (int j = 0; j < 4; ++j) acc[i][j] = (f32x4){0.f, 0.f, 0.f, 0.f};

    int srow = lane >> 2;
    int scol = (lane & 3) * 8;
    int fr = lane & 15;
    int fk = (lane >> 4) * 8;

    for (int kb = 0; kb < 1024; kb += 32) {
#pragma unroll
        for (int cc = 0; cc < 2; ++cc) {
            int c = wave + cc * 4;
            int r = c * 16 + srow;
            gl_lds16(A + (size_t)(row0 + r) * 1024 + kb + scol, &As[c * 512 + lane * 8]);
            gl_lds16(Bt + (size_t)(col0 + r) * 1024 + kb + scol, &Bs[c * 512 + lane * 8]);
        }
        __syncthreads();

        half8 af[4], bf[4];
#pragma unroll
        for (int i = 0; i < 4; ++i)
            af[i] = *(const half8*)&As[(wr * 64 + i * 16 + fr) * 32 + fk];
#pragma unroll
        for (int j = 0; j < 4; ++j)
            bf[j] = *(const half8*)&Bs[(wc * 64 + j * 16 + fr) * 32 + fk];
#pragma unroll
        for (int i = 0; i < 4; ++i)
#pragma unroll
            for (int j = 0; j < 4; ++j)
                acc[i][j] = __builtin_amdgcn_mfma_f32_16x16x32_f16(af[i], bf[j], acc[i][j],
                                                                   0, 0, 0);
        __syncthreads();
    }

    int cn = lane & 15, rq = (lane >> 4) * 4;
#pragma unroll
    for (int i = 0; i < 4; ++i) {
        int rbase = row0 + wr * 64 + i * 16 + rq;
#pragma unroll
        for (int j = 0; j < 4; ++j) {
            int col = col0 + wc * 64 + j * 16 + cn;
#pragma unroll
            for (int r = 0; r < 4; ++r) {
                int row = rbase + r;
                if (row < Nn) C16[(size_t)row * HC + col] = (_Float16)acc[i][j][r];
            }
        }
    }
}

// ---------------- attention ----------------

__global__ __launch_bounds__(256) void attn_nodes_k(const _Float16* __restrict__ xl16,
                                                    const float* __restrict__ a_s,
                                                    const float* __restrict__ a_d,
                                                    float* __restrict__ a_src,
                                                    float* __restrict__ a_dst) {
    int wid = (blockIdx.x * 256 + threadIdx.x) >> 6;
    int lane = threadIdx.x & 63;
    if (wid >= Nn * Hh) return;
    int n = wid >> 3, h = wid & 7;
    const _Float16* row = xl16 + (size_t)n * HC + h * Cc;
    float c0 = (float)row[lane * 2], c1 = (float)row[lane * 2 + 1];
    float2 sv = *(const float2*)&a_s[h * Cc + lane * 2];
    float2 dv = *(const float2*)&a_d[h * Cc + lane * 2];
    float s1 = c0 * sv.x + c1 * sv.y;
    float s2 = c0 * dv.x + c1 * dv.y;
#pragma unroll
    for (int off = 32; off; off >>= 1) {
        s1 += __shfl_xor(s1, off);
        s2 += __shfl_xor(s2, off);
    }
    if (lane == 0) { a_src[wid] = s1; a_dst[wid] = s2; }
}

__global__ void alpha_edge_k(const int* __restrict__ src, const int* __restrict__ dst,
                             const int* __restrict__ epos, const float* __restrict__ ea,
                             const float* __restrict__ a_src, const float* __restrict__ a_dst,
                             const float* __restrict__ w_ae, float* __restrict__ alphaP) {
    int e = blockIdx.x * 256 + threadIdx.x;
    if (e >= En) return;
    int s = src[e], d = dst[e];
    int pos = epos[e];
    float f0 = ea[e * 3 + 0], f1 = ea[e * 3 + 1], f2 = ea[e * 3 + 2];
#pragma unroll
    for (int h = 0; h < Hh; ++h) {
        float v = a_src[s * Hh + h] + a_dst[d * Hh + h]
                + f0 * w_ae[h] + f1 * w_ae[Hh + h] + f2 * w_ae[2 * Hh + h];
        alphaP[(size_t)pos * Hh + h] = (v > 0.f) ? v : 0.2f * v;
    }
}

// ONE WAVE PER NODE, all 8 heads.
// mode 0: out = elu(agg+bias) -> fp16 into A2 (next GEMM input)
// mode 1: head-mean+bias+elu, dot with lin_w -> dnode[n] (scalar)
__global__ __launch_bounds__(256) void aggregate_k(const _Float16* __restrict__ xl16,
                                                   const float* __restrict__ alphaP,
                                                   const float* __restrict__ loop_attr,
                                                   const float* __restrict__ a_srcB,
                                                   const float* __restrict__ a_dstB,
                                                   const float* __restrict__ w_ae,
                                                   const int* __restrict__ rowptr,
                                                   const int* __restrict__ srcP,
                                                   const float* __restrict__ bias,
                                                   const float* __restrict__ lin_w,
                                                   _Float16* __restrict__ A2,
                                                   float* __restrict__ dnode,
                                                   int raw_mode) {
    int n = (blockIdx.x * 256 + threadIdx.x) >> 6;
    int lane = threadIdx.x & 63;
    if (n >= Nn) return;
    int beg = rowptr[n], end = rowptr[n + 1];
    int hh = lane & 7;      // phase-1 head
    int slot = lane >> 3;
    int hc = lane >> 3;     // phase-2 head (channel block)

    float f0 = loop_attr[n * 3 + 0], f1 = loop_attr[n * 3 + 1], f2 = loop_attr[n * 3 + 2];
    float av = a_srcB[n * 8 + hh] + a_dstB[n * 8 + hh]
             + f0 * w_ae[hh] + f1 * w_ae[8 + hh] + f2 * w_ae[16 + hh];
    float aself = (av > 0.f) ? av : 0.2f * av;

    // phase 1: online softmax stats, 8 edges x 8 heads per sweep
    float m = (slot == 0) ? aself : -3.0e38f;
    float s = (slot == 0) ? 1.0f : 0.0f;
    for (int i = beg + slot; i < end; i += 8) {
        float a = alphaP[(size_t)i * 8 + hh];
        if (a > m) { s = s * __expf(m - a) + 1.0f; m = a; }
        else s += __expf(a - m);
    }
#pragma unroll
    for (int off = 8; off < 64; off <<= 1) {
        float mo = __shfl_xor(m, off);
        float so = __shfl_xor(s, off);
        float M = fmaxf(m, mo);
        s = s * __expf(m - M) + so * __expf(mo - M);
        m = M;
    }
    float inv = 1.f / (s + 1e-16f);
    float wself = __expf(aself - m) * inv;

    float m_c = __shfl(m, hc);
    float inv_c = __shfl(inv, hc);
    float wself_c = __shfl(wself, hc);

    // phase 2: gather. lane reads halfs [lane*16, lane*16+16)
    float acc[16];
    {
        const _Float16* r = xl16 + (size_t)n * HC + lane * 16;
        half8 r0 = *(const half8*)r;
        half8 r1 = *(const half8*)(r + 8);
#pragma unroll
        for (int j = 0; j < 8; ++j) {
            acc[j] = wself_c * (float)r0[j];
            acc[8 + j] = wself_c * (float)r1[j];
        }
    }
    for (int i = beg; i < end; ++i) {
        float a = alphaP[(size_t)i * 8 + hc];
        float w = __expf(a - m_c) * inv_c;
        int sn = srcP[i];
        const _Float16* r = xl16 + (size_t)sn * HC + lane * 16;
        half8 r0 = *(const half8*)r;
        half8 r1 = *(const half8*)(r + 8);
#pragma unroll
        for (int j = 0; j < 8; ++j) {
            acc[j] = fmaf(w, (float)r0[j], acc[j]);
            acc[8 + j] = fmaf(w, (float)r1[j], acc[8 + j]);
        }
    }

    if (!raw_mode) {
        int ch = lane * 16;
        half8 hv0, hv1;
#pragma unroll
        for (int j = 0; j < 8; ++j) {
            hv0[j] = (_Float16)elu_f(acc[j] + bias[ch + j]);
            hv1[j] = (_Float16)elu_f(acc[8 + j] + bias[ch + 8 + j]);
        }
        _Float16* p = A2 + (size_t)n * 1024 + ch;
        *(half8*)p = hv0;
        *(half8*)(p + 8) = hv1;
    } else {
        // head-mean: sum over the 8 lanes sharing lane&7 (xor bits 3..5)
#pragma unroll
        for (int off = 8; off < 64; off <<= 1)
#pragma unroll
            for (int j = 0; j < 16; ++j) acc[j] += __shfl_xor(acc[j], off);
        // every lane now holds head-summed channels (lane&7)*16 + j
        int c0 = (lane & 7) * 16;
        float partial = 0.f;
#pragma unroll
        for (int j = 0; j < 16; ++j) {
            float v = elu_f(acc[j] * 0.125f + bias[c0 + j]);
            partial = fmaf(v, lin_w[c0 + j], partial);
        }
#pragma unroll
        for (int off = 1; off < 8; off <<= 1) partial += __shfl_xor(partial, off);
        if (lane == 0) dnode[n] = partial;
    }
}

// ---------------- pooling: reduce per-node scalars per group ----------------

__global__ __launch_bounds__(256) void pool_final_k(const float* __restrict__ dnode,
                                                    const int* __restrict__ gstart,
                                                    const float* __restrict__ lin_b,
                                                    float* __restrict__ out) {
    __shared__ float sh[256];
    int g = blockIdx.x;
    int tid = threadIdx.x;
    int s = gstart[g], e = gstart[g + 1];
    float acc = 0.f;
    for (int n = s + tid; n < e; n += 256) acc += dnode[n];
    sh[tid] = acc;
    __syncthreads();
    for (int off = 128; off; off >>= 1) {
        if (tid < off) sh[tid] += sh[tid + off];
        __syncthreads();
    }
    if (tid == 0) out[g] = sh[0] / fmaxf((float)(e - s), 1.f) + lin_b[0];
}

// ---------------- launch ----------------

extern "C" void kernel_launch(void* const* d_in, const int* in_sizes, int n_in,
                              void* d_out, int out_size, void* d_ws, size_t ws_size,
                              hipStream_t stream) {
    const float* x = (const float*)d_in[0];
    const int* ei = (const int*)d_in[1];
    const float* ea = (const float*)d_in[2];
    const int* batch = (const int*)d_in[3];
    const float *Wl[4], *Wel[4], *asl[4], *adl[4], *ael[4], *bl[4];
    for (int l = 0; l < 4; ++l) {
        Wl[l] = (const float*)d_in[4 + 6 * l];
        Wel[l] = (const float*)d_in[5 + 6 * l];
        asl[l] = (const float*)d_in[6 + 6 * l];
        adl[l] = (const float*)d_in[7 + 6 * l];
        ael[l] = (const float*)d_in[8 + 6 * l];
        bl[l] = (const float*)d_in[9 + 6 * l];
    }
    const float* lin_w = (const float*)d_in[28];
    const float* lin_b = (const float*)d_in[29];
    const int* srcA = ei;
    const int* dstA = ei + En;

    float* Wp = (float*)d_ws;
    size_t o = 0;
    _Float16* A2 = (_Float16*)(Wp + o); o += (size_t)Mpad * 512;         // elu acts fp16
    _Float16* Wt16 = (_Float16*)(Wp + o); o += (size_t)3 * HC * HC / 2;  // 3 fp16 W^T
    _Float16* xl16 = (_Float16*)(Wp + o); o += (size_t)Nn * HC / 2;      // xl fp16
    float* alphaP = Wp + o; o += (size_t)En * Hh;
    float* loop_attr = Wp + o; o += Nn * 3;
    int* cnt = (int*)(Wp + o); o += Nn;
    int* rowptr = (int*)(Wp + o); o += Nn + 1;
    int* fillptr = (int*)(Wp + o); o += Nn;
    int* epos = (int*)(Wp + o); o += En;
    int* srcP = (int*)(Wp + o); o += En;
    int* gstart = (int*)(Wp + o); o += Gg + 1;
    float* a_srcB = Wp + o; o += Nn * Hh;
    float* a_dstB = Wp + o; o += Nn * Hh;
    float* w_ae_all = Wp + o; o += 128;
    float* dnode = Wp + o; o += Nn;

    hipMemsetAsync(cnt, 0, Nn * sizeof(int), stream);
    hipMemsetAsync(loop_attr, 0, Nn * 3 * sizeof(float), stream);

    deg_sum_k<<<(En + 255) / 256, 256, 0, stream>>>(dstA, ea, cnt, loop_attr);
    finish_loop_k<<<(Nn + 255) / 256, 256, 0, stream>>>(cnt, loop_attr);
    scan_k<<<1, 1024, 0, stream>>>(cnt, rowptr, fillptr);
    csr_fill_k<<<(En + 255) / 256, 256, 0, stream>>>(srcA, dstA, fillptr, epos, srcP);
    bounds_k<<<(Nn + 255) / 256, 256, 0, stream>>>(batch, gstart);
    wae_all_k<<<1, 128, 0, stream>>>(Wel[0], ael[0], Wel[1], ael[1], Wel[2], ael[2],
                                     Wel[3], ael[3], w_ae_all);
    wsplit_all_k<<<dim3(32, 32, 3), dim3(32, 32), 0, stream>>>(Wl[1], Wl[2], Wl[3], Wt16);

    for (int l = 0; l < 4; ++l) {
        if (l == 0)
            gemm_k5<<<Nn, 256, 0, stream>>>(x, Wl[0], xl16);
        else
            gemm_mfma<<<dim3(HC / 128, Mpad / 128), 256, 0, stream>>>(
                A2, Wt16 + (size_t)(l - 1) * HC * HC, xl16);
        attn_nodes_k<<<(Nn * Hh) / 4, 256, 0, stream>>>(xl16, asl[l], adl[l], a_srcB, a_dstB);
        alpha_edge_k<<<(En + 255) / 256, 256, 0, stream>>>(srcA, dstA, epos, ea, a_srcB,
                                                           a_dstB, w_ae_all + l * 24, alphaP);
        aggregate_k<<<(Nn + 3) / 4, 256, 0, stream>>>(xl16, alphaP, loop_attr, a_srcB,
                                                      a_dstB, w_ae_all + l * 24, rowptr,
                                                      srcP, bl[l], lin_w, A2, dnode,
                                                      (l == 3) ? 1 : 0);
    }
    pool_final_k<<<Gg, 256, 0, stream>>>(dnode, gstart, lin_b, (float*)d_out);
}

// Round 6
// 642.025 us; speedup vs baseline: 3.1221x; 1.0158x over previous
//
#include <hip/hip_runtime.h>
#include <math.h>

#define Nn 10000
#define En 160000
#define NF 5
#define EF 3
#define Hh 8
#define Cc 128
#define HC 1024
#define Gg 16

#define Mpad 10112   // 79 * 128

typedef __attribute__((ext_vector_type(8))) _Float16 half8;
typedef __attribute__((ext_vector_type(4))) float f32x4;

// ---------------- helpers ----------------

__device__ __forceinline__ void gl_lds16(const void* g, void* l) {
    __builtin_amdgcn_global_load_lds((const __attribute__((address_space(1))) void*)g,
                                     (__attribute__((address_space(3))) void*)l, 16, 0, 0);
}

__device__ __forceinline__ float elu_f(float v) {
    return (v > 0.f) ? v : expm1f(v);
}

// ---------------- preprocessing ----------------

__global__ void deg_sum_k(const int* __restrict__ dst, const float* __restrict__ ea,
                          int* __restrict__ cnt, float* __restrict__ sum_ea) {
    int e = blockIdx.x * 256 + threadIdx.x;
    if (e >= En) return;
    int d = dst[e];
    atomicAdd(&cnt[d], 1);
    atomicAdd(&sum_ea[d * 3 + 0], ea[e * 3 + 0]);
    atomicAdd(&sum_ea[d * 3 + 1], ea[e * 3 + 1]);
    atomicAdd(&sum_ea[d * 3 + 2], ea[e * 3 + 2]);
}

__global__ void finish_loop_k(const int* __restrict__ cnt, float* __restrict__ loop_attr) {
    int n = blockIdx.x * 256 + threadIdx.x;
    if (n >= Nn) return;
    float s = 1.0f / fmaxf((float)cnt[n], 1.0f);
    loop_attr[n * 3 + 0] *= s;
    loop_attr[n * 3 + 1] *= s;
    loop_attr[n * 3 + 2] *= s;
}

__global__ __launch_bounds__(1024) void scan_k(const int* __restrict__ cnt,
                                               int* __restrict__ rowptr,
                                               int* __restrict__ fillptr) {
    __shared__ int sh[1024];
    int tid = threadIdx.x;
    int base = 0;
    for (int chunk = 0; chunk < Nn; chunk += 1024) {
        int i = chunk + tid;
        int v = (i < Nn) ? cnt[i] : 0;
        sh[tid] = v;
        __syncthreads();
        for (int off = 1; off < 1024; off <<= 1) {
            int t = (tid >= off) ? sh[tid - off] : 0;
            __syncthreads();
            sh[tid] += t;
            __syncthreads();
        }
        int excl = sh[tid] - v;
        if (i < Nn) { rowptr[i] = base + excl; fillptr[i] = base + excl; }
        int total = sh[1023];
        __syncthreads();
        base += total;
    }
    if (tid == 0) rowptr[Nn] = base;
}

__global__ void csr_fill_k(const int* __restrict__ src, const int* __restrict__ dst,
                           int* __restrict__ fillptr, int* __restrict__ epos,
                           int* __restrict__ srcP) {
    int e = blockIdx.x * 256 + threadIdx.x;
    if (e >= En) return;
    int d = dst[e];
    int pos = atomicAdd(&fillptr[d], 1);
    epos[e] = pos;
    srcP[pos] = src[e];
}

// group boundaries from sorted batch
__global__ void bounds_k(const int* __restrict__ batch, int* __restrict__ gstart) {
    int i = blockIdx.x * 256 + threadIdx.x;
    if (i >= Nn) return;
    int b = batch[i];
    if (i == 0) {
        for (int g = 0; g <= b; ++g) gstart[g] = 0;
    } else {
        int pb = batch[i - 1];
        for (int g = pb + 1; g <= b; ++g) gstart[g] = i;
    }
    if (i == Nn - 1) {
        for (int g = b + 1; g <= Gg; ++g) gstart[g] = Nn;
    }
}

// ---------------- weight prep (once, all layers) ----------------

__global__ void wae_all_k(const float* __restrict__ We1, const float* __restrict__ ae1,
                          const float* __restrict__ We2, const float* __restrict__ ae2,
                          const float* __restrict__ We3, const float* __restrict__ ae3,
                          const float* __restrict__ We4, const float* __restrict__ ae4,
                          float* __restrict__ w_ae_all) {
    int t = threadIdx.x;
    if (t >= 96) return;
    int l = t / 24, idx = t % 24;
    int f = idx >> 3, h = idx & 7;
    const float* We = (l == 0) ? We1 : (l == 1) ? We2 : (l == 2) ? We3 : We4;
    const float* ae = (l == 0) ? ae1 : (l == 1) ? ae2 : (l == 2) ? ae3 : ae4;
    float s = 0.f;
    for (int c = 0; c < Cc; ++c) s += We[f * HC + h * Cc + c] * ae[h * Cc + c];
    w_ae_all[l * 24 + f * 8 + h] = s;
}

__global__ __launch_bounds__(1024) void wsplit_all_k(const float* __restrict__ W2,
                                                     const float* __restrict__ W3,
                                                     const float* __restrict__ W4,
                                                     _Float16* __restrict__ Wt16) {
    __shared__ float tile[32][33];
    int z = blockIdx.z;
    const float* W = (z == 0) ? W2 : (z == 1) ? W3 : W4;
    int nb = blockIdx.x * 32, kb = blockIdx.y * 32;
    tile[threadIdx.y][threadIdx.x] = W[(size_t)(kb + threadIdx.y) * HC + nb + threadIdx.x];
    __syncthreads();
    float x = tile[threadIdx.x][threadIdx.y];   // W[kb+tx][nb+ty]
    int n = nb + threadIdx.y, k = kb + threadIdx.x;
    Wt16[(size_t)z * HC * HC + (size_t)n * HC + k] = (_Float16)x;
}

// ---------------- GEMMs ----------------

__global__ void gemm_k5(const float* __restrict__ x, const float* __restrict__ Wm,
                        _Float16* __restrict__ out16) {
    int n = blockIdx.x;
    int tid = threadIdx.x;
    __shared__ float xr[8];
    if (tid < NF) xr[tid] = x[n * NF + tid];
    __syncthreads();
    float x0 = xr[0], x1 = xr[1], x2 = xr[2], x3 = xr[3], x4 = xr[4];
    for (int j = tid; j < HC; j += 256) {
        float v = x0 * Wm[j] + x1 * Wm[HC + j] + x2 * Wm[2 * HC + j]
                + x3 * Wm[3 * HC + j] + x4 * Wm[4 * HC + j];
        out16[(size_t)n * HC + j] = (_Float16)v;
    }
}

// pure fp16 MFMA GEMM: C16 = A * W^T-tiles (m97 structure, 16 KB LDS)
__global__ __launch_bounds__(256) void gemm_mfma(const _Float16* __restrict__ A,
                                                 const _Float16* __restrict__ Bt,
                                                 _Float16* __restrict__ C16) {
    __shared__ _Float16 As[128 * 32];
    __shared__ _Float16 Bs[128 * 32];
    int tid = threadIdx.x;
    int wave = tid >> 6, lane = tid & 63;
    int wr = wave >> 1, wc = wave & 1;
    int row0 = blockIdx.y * 128;
    int col0 = blockIdx.x * 128;

    f32x4 acc[4][4];
#pragma unroll
    for (int i = 0; i < 4; ++i)
#pragma unroll
        for (int j = 0; j < 4; ++j) acc[i][j] = (f32x4){0.f, 0.f, 0.f, 0.f};

    int srow = lane >> 2;
    int scol = (lane & 3) * 8;
    int fr = lane & 15;
    int fk = (lane >> 4) * 8;

    for (int kb = 0; kb < 1024; kb += 32) {
#pragma unroll
        for (int cc = 0; cc < 2; ++cc) {
            int c = wave + cc * 4;
            int r = c * 16 + srow;
            gl_lds16(A + (size_t)(row0 + r) * 1024 + kb + scol, &As[c * 512 + lane * 8]);
            gl_lds16(Bt + (size_t)(col0 + r) * 1024 + kb + scol, &Bs[c * 512 + lane * 8]);
        }
        __syncthreads();

        half8 af[4], bf[4];
#pragma unroll
        for (int i = 0; i < 4; ++i)
            af[i] = *(const half8*)&As[(wr * 64 + i * 16 + fr) * 32 + fk];
#pragma unroll
        for (int j = 0; j < 4; ++j)
            bf[j] = *(const half8*)&Bs[(wc * 64 + j * 16 + fr) * 32 + fk];
#pragma unroll
        for (int i = 0; i < 4; ++i)
#pragma unroll
            for (int j = 0; j < 4; ++j)
                acc[i][j] = __builtin_amdgcn_mfma_f32_16x16x32_f16(af[i], bf[j], acc[i][j],
                                                                   0, 0, 0);
        __syncthreads();
    }

    int cn = lane & 15, rq = (lane >> 4) * 4;
#pragma unroll
    for (int i = 0; i < 4; ++i) {
        int rbase = row0 + wr * 64 + i * 16 + rq;
#pragma unroll
        for (int j = 0; j < 4; ++j) {
            int col = col0 + wc * 64 + j * 16 + cn;
#pragma unroll
            for (int r = 0; r < 4; ++r) {
                int row = rbase + r;
                if (row < Nn) C16[(size_t)row * HC + col] = (_Float16)acc[i][j][r];
            }
        }
    }
}

// ---------------- attention ----------------

__global__ __launch_bounds__(256) void attn_nodes_k(const _Float16* __restrict__ xl16,
                                                    const float* __restrict__ a_s,
                                                    const float* __restrict__ a_d,
                                                    float* __restrict__ a_src,
                                                    float* __restrict__ a_dst) {
    int wid = (blockIdx.x * 256 + threadIdx.x) >> 6;
    int lane = threadIdx.x & 63;
    if (wid >= Nn * Hh) return;
    int n = wid >> 3, h = wid & 7;
    const _Float16* row = xl16 + (size_t)n * HC + h * Cc;
    float c0 = (float)row[lane * 2], c1 = (float)row[lane * 2 + 1];
    float2 sv = *(const float2*)&a_s[h * Cc + lane * 2];
    float2 dv = *(const float2*)&a_d[h * Cc + lane * 2];
    float s1 = c0 * sv.x + c1 * sv.y;
    float s2 = c0 * dv.x + c1 * dv.y;
#pragma unroll
    for (int off = 32; off; off >>= 1) {
        s1 += __shfl_xor(s1, off);
        s2 += __shfl_xor(s2, off);
    }
    if (lane == 0) { a_src[wid] = s1; a_dst[wid] = s2; }
}

__global__ void alpha_edge_k(const int* __restrict__ src, const int* __restrict__ dst,
                             const int* __restrict__ epos, const float* __restrict__ ea,
                             const float* __restrict__ a_src, const float* __restrict__ a_dst,
                             const float* __restrict__ w_ae, float* __restrict__ alphaP) {
    int e = blockIdx.x * 256 + threadIdx.x;
    if (e >= En) return;
    int s = src[e], d = dst[e];
    int pos = epos[e];
    float f0 = ea[e * 3 + 0], f1 = ea[e * 3 + 1], f2 = ea[e * 3 + 2];
#pragma unroll
    for (int h = 0; h < Hh; ++h) {
        float v = a_src[s * Hh + h] + a_dst[d * Hh + h]
                + f0 * w_ae[h] + f1 * w_ae[Hh + h] + f2 * w_ae[2 * Hh + h];
        alphaP[(size_t)pos * Hh + h] = (v > 0.f) ? v : 0.2f * v;
    }
}

// ONE WAVE PER NODE, all 8 heads. Gather loop 4-deep software pipelined.
// mode 0: out = elu(agg+bias) -> fp16 into A2 (next GEMM input)
// mode 1: head-mean+bias+elu, dot with lin_w -> dnode[n] (scalar)
__global__ __launch_bounds__(256) void aggregate_k(const _Float16* __restrict__ xl16,
                                                   const float* __restrict__ alphaP,
                                                   const float* __restrict__ loop_attr,
                                                   const float* __restrict__ a_srcB,
                                                   const float* __restrict__ a_dstB,
                                                   const float* __restrict__ w_ae,
                                                   const int* __restrict__ rowptr,
                                                   const int* __restrict__ srcP,
                                                   const float* __restrict__ bias,
                                                   const float* __restrict__ lin_w,
                                                   _Float16* __restrict__ A2,
                                                   float* __restrict__ dnode,
                                                   int raw_mode) {
    int n = (blockIdx.x * 256 + threadIdx.x) >> 6;
    int lane = threadIdx.x & 63;
    if (n >= Nn) return;
    int beg = rowptr[n], end = rowptr[n + 1];
    int hh = lane & 7;      // phase-1 head
    int slot = lane >> 3;
    int hc = lane >> 3;     // phase-2 head (channel block)

    float f0 = loop_attr[n * 3 + 0], f1 = loop_attr[n * 3 + 1], f2 = loop_attr[n * 3 + 2];
    float av = a_srcB[n * 8 + hh] + a_dstB[n * 8 + hh]
             + f0 * w_ae[hh] + f1 * w_ae[8 + hh] + f2 * w_ae[16 + hh];
    float aself = (av > 0.f) ? av : 0.2f * av;

    // phase 1: online softmax stats, 8 edges x 8 heads per sweep
    float m = (slot == 0) ? aself : -3.0e38f;
    float s = (slot == 0) ? 1.0f : 0.0f;
    for (int i = beg + slot; i < end; i += 8) {
        float a = alphaP[(size_t)i * 8 + hh];
        if (a > m) { s = s * __expf(m - a) + 1.0f; m = a; }
        else s += __expf(a - m);
    }
#pragma unroll
    for (int off = 8; off < 64; off <<= 1) {
        float mo = __shfl_xor(m, off);
        float so = __shfl_xor(s, off);
        float M = fmaxf(m, mo);
        s = s * __expf(m - M) + so * __expf(mo - M);
        m = M;
    }
    float inv = 1.f / (s + 1e-16f);
    float wself = __expf(aself - m) * inv;

    float m_c = __shfl(m, hc);
    float inv_c = __shfl(inv, hc);
    float wself_c = __shfl(wself, hc);

    // phase 2: gather, 4 edges per iteration with all loads hoisted
    float acc[16];
    {
        const _Float16* r = xl16 + (size_t)n * HC + lane * 16;
        half8 r0 = *(const half8*)r;
        half8 r1 = *(const half8*)(r + 8);
#pragma unroll
        for (int j = 0; j < 8; ++j) {
            acc[j] = wself_c * (float)r0[j];
            acc[8 + j] = wself_c * (float)r1[j];
        }
    }
    int loff = lane * 16;
    for (int i0 = beg; i0 < end; i0 += 4) {
        int last = end - 1;
        int i1 = (i0 + 1 < end) ? i0 + 1 : last;
        int i2 = (i0 + 2 < end) ? i0 + 2 : last;
        int i3 = (i0 + 3 < end) ? i0 + 3 : last;
        // index + alpha loads (independent)
        int s0 = srcP[i0], s1 = srcP[i1], s2 = srcP[i2], s3 = srcP[i3];
        float a0 = alphaP[(size_t)i0 * 8 + hc];
        float a1 = (i0 + 1 < end) ? alphaP[(size_t)i1 * 8 + hc] : -3.0e38f;
        float a2 = (i0 + 2 < end) ? alphaP[(size_t)i2 * 8 + hc] : -3.0e38f;
        float a3 = (i0 + 3 < end) ? alphaP[(size_t)i3 * 8 + hc] : -3.0e38f;
        // row loads (8 x 16B, independent, all in flight)
        const _Float16* p0 = xl16 + (size_t)s0 * HC + loff;
        const _Float16* p1 = xl16 + (size_t)s1 * HC + loff;
        const _Float16* p2 = xl16 + (size_t)s2 * HC + loff;
        const _Float16* p3 = xl16 + (size_t)s3 * HC + loff;
        half8 q0a = *(const half8*)p0, q0b = *(const half8*)(p0 + 8);
        half8 q1a = *(const half8*)p1, q1b = *(const half8*)(p1 + 8);
        half8 q2a = *(const half8*)p2, q2b = *(const half8*)(p2 + 8);
        half8 q3a = *(const half8*)p3, q3b = *(const half8*)(p3 + 8);
        float w0 = __expf(a0 - m_c) * inv_c;
        float w1 = __expf(a1 - m_c) * inv_c;
        float w2 = __expf(a2 - m_c) * inv_c;
        float w3 = __expf(a3 - m_c) * inv_c;
#pragma unroll
        for (int j = 0; j < 8; ++j) {
            float t0 = acc[j], t1 = acc[8 + j];
            t0 = fmaf(w0, (float)q0a[j], t0);  t1 = fmaf(w0, (float)q0b[j], t1);
            t0 = fmaf(w1, (float)q1a[j], t0);  t1 = fmaf(w1, (float)q1b[j], t1);
            t0 = fmaf(w2, (float)q2a[j], t0);  t1 = fmaf(w2, (float)q2b[j], t1);
            t0 = fmaf(w3, (float)q3a[j], t0);  t1 = fmaf(w3, (float)q3b[j], t1);
            acc[j] = t0; acc[8 + j] = t1;
        }
    }

    if (!raw_mode) {
        int ch = lane * 16;
        half8 hv0, hv1;
#pragma unroll
        for (int j = 0; j < 8; ++j) {
            hv0[j] = (_Float16)elu_f(acc[j] + bias[ch + j]);
            hv1[j] = (_Float16)elu_f(acc[8 + j] + bias[ch + 8 + j]);
        }
        _Float16* p = A2 + (size_t)n * 1024 + ch;
        *(half8*)p = hv0;
        *(half8*)(p + 8) = hv1;
    } else {
        // head-mean: sum over the 8 lanes sharing lane&7 (xor bits 3..5)
#pragma unroll
        for (int off = 8; off < 64; off <<= 1)
#pragma unroll
            for (int j = 0; j < 16; ++j) acc[j] += __shfl_xor(acc[j], off);
        int c0 = (lane & 7) * 16;
        float partial = 0.f;
#pragma unroll
        for (int j = 0; j < 16; ++j) {
            float v = elu_f(acc[j] * 0.125f + bias[c0 + j]);
            partial = fmaf(v, lin_w[c0 + j], partial);
        }
#pragma unroll
        for (int off = 1; off < 8; off <<= 1) partial += __shfl_xor(partial, off);
        if (lane == 0) dnode[n] = partial;
    }
}

// ---------------- pooling: reduce per-node scalars per group ----------------

__global__ __launch_bounds__(256) void pool_final_k(const float* __restrict__ dnode,
                                                    const int* __restrict__ gstart,
                                                    const float* __restrict__ lin_b,
                                                    float* __restrict__ out) {
    __shared__ float sh[256];
    int g = blockIdx.x;
    int tid = threadIdx.x;
    int s = gstart[g], e = gstart[g + 1];
    float acc = 0.f;
    for (int n = s + tid; n < e; n += 256) acc += dnode[n];
    sh[tid] = acc;
    __syncthreads();
    for (int off = 128; off; off >>= 1) {
        if (tid < off) sh[tid] += sh[tid + off];
        __syncthreads();
    }
    if (tid == 0) out[g] = sh[0] / fmaxf((float)(e - s), 1.f) + lin_b[0];
}

// ---------------- launch ----------------

extern "C" void kernel_launch(void* const* d_in, const int* in_sizes, int n_in,
                              void* d_out, int out_size, void* d_ws, size_t ws_size,
                              hipStream_t stream) {
    const float* x = (const float*)d_in[0];
    const int* ei = (const int*)d_in[1];
    const float* ea = (const float*)d_in[2];
    const int* batch = (const int*)d_in[3];
    const float *Wl[4], *Wel[4], *asl[4], *adl[4], *ael[4], *bl[4];
    for (int l = 0; l < 4; ++l) {
        Wl[l] = (const float*)d_in[4 + 6 * l];
        Wel[l] = (const float*)d_in[5 + 6 * l];
        asl[l] = (const float*)d_in[6 + 6 * l];
        adl[l] = (const float*)d_in[7 + 6 * l];
        ael[l] = (const float*)d_in[8 + 6 * l];
        bl[l] = (const float*)d_in[9 + 6 * l];
    }
    const float* lin_w = (const float*)d_in[28];
    const float* lin_b = (const float*)d_in[29];
    const int* srcA = ei;
    const int* dstA = ei + En;

    float* Wp = (float*)d_ws;
    size_t o = 0;
    _Float16* A2 = (_Float16*)(Wp + o); o += (size_t)Mpad * 512;         // elu acts fp16
    _Float16* Wt16 = (_Float16*)(Wp + o); o += (size_t)3 * HC * HC / 2;  // 3 fp16 W^T
    _Float16* xl16 = (_Float16*)(Wp + o); o += (size_t)Nn * HC / 2;      // xl fp16
    float* alphaP = Wp + o; o += (size_t)En * Hh;
    float* loop_attr = Wp + o; o += Nn * 3;
    int* cnt = (int*)(Wp + o); o += Nn;
    int* rowptr = (int*)(Wp + o); o += Nn + 1;
    int* fillptr = (int*)(Wp + o); o += Nn;
    int* epos = (int*)(Wp + o); o += En;
    int* srcP = (int*)(Wp + o); o += En;
    int* gstart = (int*)(Wp + o); o += Gg + 1;
    float* a_srcB = Wp + o; o += Nn * Hh;
    float* a_dstB = Wp + o; o += Nn * Hh;
    float* w_ae_all = Wp + o; o += 128;
    float* dnode = Wp + o; o += Nn;

    hipMemsetAsync(cnt, 0, Nn * sizeof(int), stream);
    hipMemsetAsync(loop_attr, 0, Nn * 3 * sizeof(float), stream);

    deg_sum_k<<<(En + 255) / 256, 256, 0, stream>>>(dstA, ea, cnt, loop_attr);
    finish_loop_k<<<(Nn + 255) / 256, 256, 0, stream>>>(cnt, loop_attr);
    scan_k<<<1, 1024, 0, stream>>>(cnt, rowptr, fillptr);
    csr_fill_k<<<(En + 255) / 256, 256, 0, stream>>>(srcA, dstA, fillptr, epos, srcP);
    bounds_k<<<(Nn + 255) / 256, 256, 0, stream>>>(batch, gstart);
    wae_all_k<<<1, 128, 0, stream>>>(Wel[0], ael[0], Wel[1], ael[1], Wel[2], ael[2],
                                     Wel[3], ael[3], w_ae_all);
    wsplit_all_k<<<dim3(32, 32, 3), dim3(32, 32), 0, stream>>>(Wl[1], Wl[2], Wl[3], Wt16);

    for (int l = 0; l < 4; ++l) {
        if (l == 0)
            gemm_k5<<<Nn, 256, 0, stream>>>(x, Wl[0], xl16);
        else
            gemm_mfma<<<dim3(HC / 128, Mpad / 128), 256, 0, stream>>>(
                A2, Wt16 + (size_t)(l - 1) * HC * HC, xl16);
        attn_nodes_k<<<(Nn * Hh) / 4, 256, 0, stream>>>(xl16, asl[l], adl[l], a_srcB, a_dstB);
        alpha_edge_k<<<(En + 255) / 256, 256, 0, stream>>>(srcA, dstA, epos, ea, a_srcB,
                                                           a_dstB, w_ae_all + l * 24, alphaP);
        aggregate_k<<<(Nn + 3) / 4, 256, 0, stream>>>(xl16, alphaP, loop_attr, a_srcB,
                                                      a_dstB, w_ae_all + l * 24, rowptr,
                                                      srcP, bl[l], lin_w, A2, dnode,
                                                      (l == 3) ? 1 : 0);
    }
    pool_final_k<<<Gg, 256, 0, stream>>>(dnode, gstart, lin_b, (float*)d_out);
}

// Round 7
// 598.970 us; speedup vs baseline: 3.3466x; 1.0719x over previous
//
#include <hip/hip_runtime.h>
#include <math.h>

#define Nn 10000
#define En 160000
#define NF 5
#define EF 3
#define Hh 8
#define Cc 128
#define HC 1024
#define Gg 16

#define Mpad 10112   // 79 * 128

typedef __attribute__((ext_vector_type(8))) _Float16 half8;
typedef __attribute__((ext_vector_type(4))) float f32x4;

// ---------------- helpers ----------------

__device__ __forceinline__ void gl_lds16(const void* g, void* l) {
    __builtin_amdgcn_global_load_lds((const __attribute__((address_space(1))) void*)g,
                                     (__attribute__((address_space(3))) void*)l, 16, 0, 0);
}

__device__ __forceinline__ float elu_f(float v) {
    return (v > 0.f) ? v : expm1f(v);
}

// ---------------- preprocessing ----------------

__global__ void deg_sum_k(const int* __restrict__ dst, const float* __restrict__ ea,
                          int* __restrict__ cnt, float* __restrict__ sum_ea) {
    int e = blockIdx.x * 256 + threadIdx.x;
    if (e >= En) return;
    int d = dst[e];
    atomicAdd(&cnt[d], 1);
    atomicAdd(&sum_ea[d * 3 + 0], ea[e * 3 + 0]);
    atomicAdd(&sum_ea[d * 3 + 1], ea[e * 3 + 1]);
    atomicAdd(&sum_ea[d * 3 + 2], ea[e * 3 + 2]);
}

__global__ void finish_loop_k(const int* __restrict__ cnt, float* __restrict__ loop_attr) {
    int n = blockIdx.x * 256 + threadIdx.x;
    if (n >= Nn) return;
    float s = 1.0f / fmaxf((float)cnt[n], 1.0f);
    loop_attr[n * 3 + 0] *= s;
    loop_attr[n * 3 + 1] *= s;
    loop_attr[n * 3 + 2] *= s;
}

__global__ __launch_bounds__(1024) void scan_k(const int* __restrict__ cnt,
                                               int* __restrict__ rowptr,
                                               int* __restrict__ fillptr) {
    __shared__ int sh[1024];
    int tid = threadIdx.x;
    int base = 0;
    for (int chunk = 0; chunk < Nn; chunk += 1024) {
        int i = chunk + tid;
        int v = (i < Nn) ? cnt[i] : 0;
        sh[tid] = v;
        __syncthreads();
        for (int off = 1; off < 1024; off <<= 1) {
            int t = (tid >= off) ? sh[tid - off] : 0;
            __syncthreads();
            sh[tid] += t;
            __syncthreads();
        }
        int excl = sh[tid] - v;
        if (i < Nn) { rowptr[i] = base + excl; fillptr[i] = base + excl; }
        int total = sh[1023];
        __syncthreads();
        base += total;
    }
    if (tid == 0) rowptr[Nn] = base;
}

// CSR fill: src node + permuted edge_attr (float4) per position
__global__ void csr_fill_k(const int* __restrict__ src, const int* __restrict__ dst,
                           const float* __restrict__ ea, int* __restrict__ fillptr,
                           int* __restrict__ srcP, float4* __restrict__ eaP) {
    int e = blockIdx.x * 256 + threadIdx.x;
    if (e >= En) return;
    int d = dst[e];
    int pos = atomicAdd(&fillptr[d], 1);
    srcP[pos] = src[e];
    eaP[pos] = make_float4(ea[e * 3 + 0], ea[e * 3 + 1], ea[e * 3 + 2], 0.f);
}

// group boundaries from sorted batch
__global__ void bounds_k(const int* __restrict__ batch, int* __restrict__ gstart) {
    int i = blockIdx.x * 256 + threadIdx.x;
    if (i >= Nn) return;
    int b = batch[i];
    if (i == 0) {
        for (int g = 0; g <= b; ++g) gstart[g] = 0;
    } else {
        int pb = batch[i - 1];
        for (int g = pb + 1; g <= b; ++g) gstart[g] = i;
    }
    if (i == Nn - 1) {
        for (int g = b + 1; g <= Gg; ++g) gstart[g] = Nn;
    }
}

// ---------------- weight prep (once, all layers) ----------------

__global__ void wae_all_k(const float* __restrict__ We1, const float* __restrict__ ae1,
                          const float* __restrict__ We2, const float* __restrict__ ae2,
                          const float* __restrict__ We3, const float* __restrict__ ae3,
                          const float* __restrict__ We4, const float* __restrict__ ae4,
                          float* __restrict__ w_ae_all) {
    int t = threadIdx.x;
    if (t >= 96) return;
    int l = t / 24, idx = t % 24;
    int f = idx >> 3, h = idx & 7;
    const float* We = (l == 0) ? We1 : (l == 1) ? We2 : (l == 2) ? We3 : We4;
    const float* ae = (l == 0) ? ae1 : (l == 1) ? ae2 : (l == 2) ? ae3 : ae4;
    float s = 0.f;
    for (int c = 0; c < Cc; ++c) s += We[f * HC + h * Cc + c] * ae[h * Cc + c];
    w_ae_all[l * 24 + f * 8 + h] = s;
}

__global__ __launch_bounds__(1024) void wsplit_all_k(const float* __restrict__ W2,
                                                     const float* __restrict__ W3,
                                                     const float* __restrict__ W4,
                                                     _Float16* __restrict__ Wt16) {
    __shared__ float tile[32][33];
    int z = blockIdx.z;
    const float* W = (z == 0) ? W2 : (z == 1) ? W3 : W4;
    int nb = blockIdx.x * 32, kb = blockIdx.y * 32;
    tile[threadIdx.y][threadIdx.x] = W[(size_t)(kb + threadIdx.y) * HC + nb + threadIdx.x];
    __syncthreads();
    float x = tile[threadIdx.x][threadIdx.y];   // W[kb+tx][nb+ty]
    int n = nb + threadIdx.y, k = kb + threadIdx.x;
    Wt16[(size_t)z * HC * HC + (size_t)n * HC + k] = (_Float16)x;
}

// ---------------- GEMMs (fused with a_src/a_dst head dots) ----------------

// layer-1 K=5 GEMM + per-head attention dots
__global__ void gemm_k5(const float* __restrict__ x, const float* __restrict__ Wm,
                        const float* __restrict__ a_s, const float* __restrict__ a_d,
                        _Float16* __restrict__ out16,
                        float* __restrict__ a_srcB, float* __restrict__ a_dstB) {
    int n = blockIdx.x;
    int tid = threadIdx.x;
    __shared__ float xr[8];
    __shared__ float vrow[HC];
    if (tid < NF) xr[tid] = x[n * NF + tid];
    __syncthreads();
    float x0 = xr[0], x1 = xr[1], x2 = xr[2], x3 = xr[3], x4 = xr[4];
    for (int j = tid; j < HC; j += 256) {
        float v = x0 * Wm[j] + x1 * Wm[HC + j] + x2 * Wm[2 * HC + j]
                + x3 * Wm[3 * HC + j] + x4 * Wm[4 * HC + j];
        out16[(size_t)n * HC + j] = (_Float16)v;
        vrow[j] = v;
    }
    __syncthreads();
    int w = tid >> 6, lane = tid & 63;
#pragma unroll
    for (int q = 0; q < 2; ++q) {
        int h = w * 2 + q;
        float v0 = vrow[h * Cc + lane], v1 = vrow[h * Cc + 64 + lane];
        float s1 = v0 * a_s[h * Cc + lane] + v1 * a_s[h * Cc + 64 + lane];
        float s2 = v0 * a_d[h * Cc + lane] + v1 * a_d[h * Cc + 64 + lane];
#pragma unroll
        for (int off = 32; off; off >>= 1) {
            s1 += __shfl_xor(s1, off);
            s2 += __shfl_xor(s2, off);
        }
        if (lane == 0) { a_srcB[n * 8 + h] = s1; a_dstB[n * 8 + h] = s2; }
    }
}

// fp16 MFMA GEMM (m97 structure) + fused per-head a_src/a_dst dots.
// blockIdx.x (col block) == head index since BN == Cc == 128.
__global__ __launch_bounds__(256) void gemm_mfma(const _Float16* __restrict__ A,
                                                 const _Float16* __restrict__ Bt,
                                                 const float* __restrict__ a_s,
                                                 const float* __restrict__ a_d,
                                                 _Float16* __restrict__ C16,
                                                 float* __restrict__ a_srcB,
                                                 float* __restrict__ a_dstB) {
    __shared__ _Float16 As[128 * 32];
    __shared__ _Float16 Bs[128 * 32];
    __shared__ float ps[128][2];
    __shared__ float pd[128][2];
    int tid = threadIdx.x;
    int wave = tid >> 6, lane = tid & 63;
    int wr = wave >> 1, wc = wave & 1;
    int row0 = blockIdx.y * 128;
    int col0 = blockIdx.x * 128;
    int h = blockIdx.x;   // head

    f32x4 acc[4][4];
#pragma unroll
    for (int i = 0; i < 4; ++i)
#pragma unroll
        for (int j = 0; j < 4; ++j) acc[i][j] = (f32x4){0.f, 0.f, 0.f, 0.f};

    int srow = lane >> 2;
    int scol = (lane & 3) * 8;
    int fr = lane & 15;
    int fk = (lane >> 4) * 8;

    for (int kb = 0; kb < 1024; kb += 32) {
#pragma unroll
        for (int cc = 0; cc < 2; ++cc) {
            int c = wave + cc * 4;
            int r = c * 16 + srow;
            gl_lds16(A + (size_t)(row0 + r) * 1024 + kb + scol, &As[c * 512 + lane * 8]);
            gl_lds16(Bt + (size_t)(col0 + r) * 1024 + kb + scol, &Bs[c * 512 + lane * 8]);
        }
        __syncthreads();

        half8 af[4], bf[4];
#pragma unroll
        for (int i = 0; i < 4; ++i)
            af[i] = *(const half8*)&As[(wr * 64 + i * 16 + fr) * 32 + fk];
#pragma unroll
        for (int j = 0; j < 4; ++j)
            bf[j] = *(const half8*)&Bs[(wc * 64 + j * 16 + fr) * 32 + fk];
#pragma unroll
        for (int i = 0; i < 4; ++i)
#pragma unroll
            for (int j = 0; j < 4; ++j)
                acc[i][j] = __builtin_amdgcn_mfma_f32_16x16x32_f16(af[i], bf[j], acc[i][j],
                                                                   0, 0, 0);
        __syncthreads();
    }

    int cn = lane & 15, rq = (lane >> 4) * 4;
    // C write
#pragma unroll
    for (int i = 0; i < 4; ++i) {
        int rbase = row0 + wr * 64 + i * 16 + rq;
#pragma unroll
        for (int j = 0; j < 4; ++j) {
            int col = col0 + wc * 64 + j * 16 + cn;
#pragma unroll
            for (int r = 0; r < 4; ++r) {
                int row = rbase + r;
                if (row < Nn) C16[(size_t)row * HC + col] = (_Float16)acc[i][j][r];
            }
        }
    }
    // fused a_src/a_dst dots over this head's 128 channels
    float asv[4], adv[4];
#pragma unroll
    for (int j = 0; j < 4; ++j) {
        int c = wc * 64 + j * 16 + cn;
        asv[j] = a_s[h * Cc + c];
        adv[j] = a_d[h * Cc + c];
    }
#pragma unroll
    for (int i = 0; i < 4; ++i)
#pragma unroll
        for (int r = 0; r < 4; ++r) {
            float rs = acc[i][0][r] * asv[0] + acc[i][1][r] * asv[1]
                     + acc[i][2][r] * asv[2] + acc[i][3][r] * asv[3];
            float rd = acc[i][0][r] * adv[0] + acc[i][1][r] * adv[1]
                     + acc[i][2][r] * adv[2] + acc[i][3][r] * adv[3];
#pragma unroll
            for (int off = 1; off < 16; off <<= 1) {
                rs += __shfl_xor(rs, off);
                rd += __shfl_xor(rd, off);
            }
            if (cn == 0) {
                int rib = wr * 64 + i * 16 + rq + r;
                ps[rib][wc] = rs;
                pd[rib][wc] = rd;
            }
        }
    __syncthreads();
    if (tid < 128) {
        int row = row0 + tid;
        if (row < Nn) {
            a_srcB[row * 8 + h] = ps[tid][0] + ps[tid][1];
            a_dstB[row * 8 + h] = pd[tid][0] + pd[tid][1];
        }
    }
}

// ---------------- fused attention aggregate ----------------

// ONE WAVE PER NODE, all 8 heads; alpha computed inline (no alphaP buffer).
// mode 0: out = elu(agg+bias) -> fp16 into A2 (next GEMM input)
// mode 1: head-mean+bias+elu, dot with lin_w -> dnode[n] (scalar)
__global__ __launch_bounds__(256) void aggregate_k(const _Float16* __restrict__ xl16,
                                                   const float4* __restrict__ eaP,
                                                   const float* __restrict__ loop_attr,
                                                   const float* __restrict__ a_srcB,
                                                   const float* __restrict__ a_dstB,
                                                   const float* __restrict__ w_ae,
                                                   const int* __restrict__ rowptr,
                                                   const int* __restrict__ srcP,
                                                   const float* __restrict__ bias,
                                                   const float* __restrict__ lin_w,
                                                   _Float16* __restrict__ A2,
                                                   float* __restrict__ dnode,
                                                   int raw_mode) {
    int n = (blockIdx.x * 256 + threadIdx.x) >> 6;
    int lane = threadIdx.x & 63;
    if (n >= Nn) return;
    int beg = rowptr[n], end = rowptr[n + 1];
    int hh = lane & 7;      // phase-1 head
    int slot = lane >> 3;
    int hc = lane >> 3;     // phase-2 head (channel block)

    float w0 = w_ae[hh], w1 = w_ae[8 + hh], w2 = w_ae[16 + hh];
    float adst_n = a_dstB[n * 8 + hh];
    float asrc_n = a_srcB[n * 8 + hh];
    float f0 = loop_attr[n * 3 + 0], f1 = loop_attr[n * 3 + 1], f2 = loop_attr[n * 3 + 2];
    float av = asrc_n + adst_n + f0 * w0 + f1 * w1 + f2 * w2;
    float aself = (av > 0.f) ? av : 0.2f * av;

    // phase 1: online softmax stats, 8 edges x 8 heads per sweep, alpha inline
    float m = (slot == 0) ? aself : -3.0e38f;
    float s = (slot == 0) ? 1.0f : 0.0f;
    for (int i = beg + slot; i < end; i += 8) {
        int sn = srcP[i];
        float4 e4 = eaP[i];
        float a = a_srcB[sn * 8 + hh] + adst_n + e4.x * w0 + e4.y * w1 + e4.z * w2;
        a = (a > 0.f) ? a : 0.2f * a;
        if (a > m) { s = s * __expf(m - a) + 1.0f; m = a; }
        else s += __expf(a - m);
    }
#pragma unroll
    for (int off = 8; off < 64; off <<= 1) {
        float mo = __shfl_xor(m, off);
        float so = __shfl_xor(s, off);
        float M = fmaxf(m, mo);
        s = s * __expf(m - M) + so * __expf(mo - M);
        m = M;
    }
    float inv = 1.f / (s + 1e-16f);
    float wself = __expf(aself - m) * inv;

    float m_c = __shfl(m, hc);
    float inv_c = __shfl(inv, hc);
    float wself_c = __shfl(wself, hc);
    float adst_nc = __shfl(adst_n, hc);
    float w0c = w_ae[hc], w1c = w_ae[8 + hc], w2c = w_ae[16 + hc];

    // phase 2: gather, 4 edges per iteration, alpha recomputed inline
    float acc[16];
    {
        const _Float16* r = xl16 + (size_t)n * HC + lane * 16;
        half8 r0 = *(const half8*)r;
        half8 r1 = *(const half8*)(r + 8);
#pragma unroll
        for (int j = 0; j < 8; ++j) {
            acc[j] = wself_c * (float)r0[j];
            acc[8 + j] = wself_c * (float)r1[j];
        }
    }
    int loff = lane * 16;
    for (int i0 = beg; i0 < end; i0 += 4) {
        int last = end - 1;
        bool v1 = (i0 + 1 < end), v2 = (i0 + 2 < end), v3 = (i0 + 3 < end);
        int i1 = v1 ? i0 + 1 : last;
        int i2 = v2 ? i0 + 2 : last;
        int i3 = v3 ? i0 + 3 : last;
        int s0 = srcP[i0], s1 = srcP[i1], s2 = srcP[i2], s3 = srcP[i3];
        float4 e0 = eaP[i0], e1 = eaP[i1], e2 = eaP[i2], e3 = eaP[i3];
        float as0 = a_srcB[s0 * 8 + hc], as1 = a_srcB[s1 * 8 + hc];
        float as2 = a_srcB[s2 * 8 + hc], as3 = a_srcB[s3 * 8 + hc];
        const _Float16* p0 = xl16 + (size_t)s0 * HC + loff;
        const _Float16* p1 = xl16 + (size_t)s1 * HC + loff;
        const _Float16* p2 = xl16 + (size_t)s2 * HC + loff;
        const _Float16* p3 = xl16 + (size_t)s3 * HC + loff;
        half8 q0a = *(const half8*)p0, q0b = *(const half8*)(p0 + 8);
        half8 q1a = *(const half8*)p1, q1b = *(const half8*)(p1 + 8);
        half8 q2a = *(const half8*)p2, q2b = *(const half8*)(p2 + 8);
        half8 q3a = *(const half8*)p3, q3b = *(const half8*)(p3 + 8);
        float al0 = as0 + adst_nc + e0.x * w0c + e0.y * w1c + e0.z * w2c;
        float al1 = as1 + adst_nc + e1.x * w0c + e1.y * w1c + e1.z * w2c;
        float al2 = as2 + adst_nc + e2.x * w0c + e2.y * w1c + e2.z * w2c;
        float al3 = as3 + adst_nc + e3.x * w0c + e3.y * w1c + e3.z * w2c;
        al0 = (al0 > 0.f) ? al0 : 0.2f * al0;
        al1 = v1 ? ((al1 > 0.f) ? al1 : 0.2f * al1) : -3.0e38f;
        al2 = v2 ? ((al2 > 0.f) ? al2 : 0.2f * al2) : -3.0e38f;
        al3 = v3 ? ((al3 > 0.f) ? al3 : 0.2f * al3) : -3.0e38f;
        float u0 = __expf(al0 - m_c) * inv_c;
        float u1 = __expf(al1 - m_c) * inv_c;
        float u2 = __expf(al2 - m_c) * inv_c;
        float u3 = __expf(al3 - m_c) * inv_c;
#pragma unroll
        for (int j = 0; j < 8; ++j) {
            float t0 = acc[j], t1 = acc[8 + j];
            t0 = fmaf(u0, (float)q0a[j], t0);  t1 = fmaf(u0, (float)q0b[j], t1);
            t0 = fmaf(u1, (float)q1a[j], t0);  t1 = fmaf(u1, (float)q1b[j], t1);
            t0 = fmaf(u2, (float)q2a[j], t0);  t1 = fmaf(u2, (float)q2b[j], t1);
            t0 = fmaf(u3, (float)q3a[j], t0);  t1 = fmaf(u3, (float)q3b[j], t1);
            acc[j] = t0; acc[8 + j] = t1;
        }
    }

    if (!raw_mode) {
        int ch = lane * 16;
        half8 hv0, hv1;
#pragma unroll
        for (int j = 0; j < 8; ++j) {
            hv0[j] = (_Float16)elu_f(acc[j] + bias[ch + j]);
            hv1[j] = (_Float16)elu_f(acc[8 + j] + bias[ch + 8 + j]);
        }
        _Float16* p = A2 + (size_t)n * 1024 + ch;
        *(half8*)p = hv0;
        *(half8*)(p + 8) = hv1;
    } else {
        // head-mean: sum over the 8 lanes sharing lane&7 (xor bits 3..5)
#pragma unroll
        for (int off = 8; off < 64; off <<= 1)
#pragma unroll
            for (int j = 0; j < 16; ++j) acc[j] += __shfl_xor(acc[j], off);
        int c0 = (lane & 7) * 16;
        float partial = 0.f;
#pragma unroll
        for (int j = 0; j < 16; ++j) {
            float v = elu_f(acc[j] * 0.125f + bias[c0 + j]);
            partial = fmaf(v, lin_w[c0 + j], partial);
        }
#pragma unroll
        for (int off = 1; off < 8; off <<= 1) partial += __shfl_xor(partial, off);
        if (lane == 0) dnode[n] = partial;
    }
}

// ---------------- pooling: reduce per-node scalars per group ----------------

__global__ __launch_bounds__(256) void pool_final_k(const float* __restrict__ dnode,
                                                    const int* __restrict__ gstart,
                                                    const float* __restrict__ lin_b,
                                                    float* __restrict__ out) {
    __shared__ float sh[256];
    int g = blockIdx.x;
    int tid = threadIdx.x;
    int s = gstart[g], e = gstart[g + 1];
    float acc = 0.f;
    for (int n = s + tid; n < e; n += 256) acc += dnode[n];
    sh[tid] = acc;
    __syncthreads();
    for (int off = 128; off; off >>= 1) {
        if (tid < off) sh[tid] += sh[tid + off];
        __syncthreads();
    }
    if (tid == 0) out[g] = sh[0] / fmaxf((float)(e - s), 1.f) + lin_b[0];
}

// ---------------- launch ----------------

extern "C" void kernel_launch(void* const* d_in, const int* in_sizes, int n_in,
                              void* d_out, int out_size, void* d_ws, size_t ws_size,
                              hipStream_t stream) {
    const float* x = (const float*)d_in[0];
    const int* ei = (const int*)d_in[1];
    const float* ea = (const float*)d_in[2];
    const int* batch = (const int*)d_in[3];
    const float *Wl[4], *Wel[4], *asl[4], *adl[4], *ael[4], *bl[4];
    for (int l = 0; l < 4; ++l) {
        Wl[l] = (const float*)d_in[4 + 6 * l];
        Wel[l] = (const float*)d_in[5 + 6 * l];
        asl[l] = (const float*)d_in[6 + 6 * l];
        adl[l] = (const float*)d_in[7 + 6 * l];
        ael[l] = (const float*)d_in[8 + 6 * l];
        bl[l] = (const float*)d_in[9 + 6 * l];
    }
    const float* lin_w = (const float*)d_in[28];
    const float* lin_b = (const float*)d_in[29];
    const int* srcA = ei;
    const int* dstA = ei + En;

    float* Wp = (float*)d_ws;
    size_t o = 0;
    _Float16* A2 = (_Float16*)(Wp + o); o += (size_t)Mpad * 512;         // elu acts fp16
    _Float16* Wt16 = (_Float16*)(Wp + o); o += (size_t)3 * HC * HC / 2;  // 3 fp16 W^T
    _Float16* xl16 = (_Float16*)(Wp + o); o += (size_t)Nn * HC / 2;      // xl fp16
    float4* eaP = (float4*)(Wp + o); o += (size_t)En * 4;                // permuted edge attr
    float* loop_attr = Wp + o; o += Nn * 3;
    int* cnt = (int*)(Wp + o); o += Nn;
    int* rowptr = (int*)(Wp + o); o += Nn + 1;
    int* fillptr = (int*)(Wp + o); o += Nn;
    int* srcP = (int*)(Wp + o); o += En;
    int* gstart = (int*)(Wp + o); o += Gg + 1;
    float* a_srcB = Wp + o; o += Nn * Hh;
    float* a_dstB = Wp + o; o += Nn * Hh;
    float* w_ae_all = Wp + o; o += 128;
    float* dnode = Wp + o; o += Nn;

    hipMemsetAsync(cnt, 0, Nn * sizeof(int), stream);
    hipMemsetAsync(loop_attr, 0, Nn * 3 * sizeof(float), stream);

    deg_sum_k<<<(En + 255) / 256, 256, 0, stream>>>(dstA, ea, cnt, loop_attr);
    finish_loop_k<<<(Nn + 255) / 256, 256, 0, stream>>>(cnt, loop_attr);
    scan_k<<<1, 1024, 0, stream>>>(cnt, rowptr, fillptr);
    csr_fill_k<<<(En + 255) / 256, 256, 0, stream>>>(srcA, dstA, ea, fillptr, srcP, eaP);
    bounds_k<<<(Nn + 255) / 256, 256, 0, stream>>>(batch, gstart);
    wae_all_k<<<1, 128, 0, stream>>>(Wel[0], ael[0], Wel[1], ael[1], Wel[2], ael[2],
                                     Wel[3], ael[3], w_ae_all);
    wsplit_all_k<<<dim3(32, 32, 3), dim3(32, 32), 0, stream>>>(Wl[1], Wl[2], Wl[3], Wt16);

    for (int l = 0; l < 4; ++l) {
        if (l == 0)
            gemm_k5<<<Nn, 256, 0, stream>>>(x, Wl[0], asl[0], adl[0], xl16, a_srcB, a_dstB);
        else
            gemm_mfma<<<dim3(HC / 128, Mpad / 128), 256, 0, stream>>>(
                A2, Wt16 + (size_t)(l - 1) * HC * HC, asl[l], adl[l], xl16, a_srcB, a_dstB);
        aggregate_k<<<(Nn + 3) / 4, 256, 0, stream>>>(xl16, eaP, loop_attr, a_srcB,
                                                      a_dstB, w_ae_all + l * 24, rowptr,
                                                      srcP, bl[l], lin_w, A2, dnode,
                                                      (l == 3) ? 1 : 0);
    }
    pool_final_k<<<Gg, 256, 0, stream>>>(dnode, gstart, lin_b, (float*)d_out);
}